// Round 9
// baseline (428.970 us; speedup 1.0000x reference)
//
#include <hip/hip_runtime.h>

// ---------------------------------------------------------------------------
// EagerAttention: x[B,T,D] -> QKV proj -> RoPE -> causal GQA attention -> out proj
// B=2 T=2048 D=2048 NH=16 NKV=4 HD=128, fp32 in/out, bf16 MFMA internally.
// ---------------------------------------------------------------------------

#define T_SZ 2048
#define D_SZ 2048
#define BT   4096   // B*T

typedef __attribute__((ext_vector_type(8))) short bf16x8;
typedef __attribute__((ext_vector_type(4))) float f32x4;

__device__ __forceinline__ unsigned short f2b(float f) {
  unsigned u = __float_as_uint(f);
  u = (u + 0x7fffu + ((u >> 16) & 1u)) >> 16;   // RNE
  return (unsigned short)u;
}
__device__ __forceinline__ float b2f(unsigned short h) {
  return __uint_as_float(((unsigned)h) << 16);
}

#if __has_builtin(__builtin_amdgcn_exp2f)
__device__ __forceinline__ float exp2_fast(float x) { return __builtin_amdgcn_exp2f(x); }
#else
__device__ __forceinline__ float exp2_fast(float x) {
  float r; asm("v_exp_f32 %0, %1" : "=v"(r) : "v"(x)); return r;
}
#endif

// async global->LDS 16B/lane: dest is wave-uniform base + lane*16
__device__ __forceinline__ void async_ld16(const void* g, void* l) {
  __builtin_amdgcn_global_load_lds(
      (const __attribute__((address_space(1))) void*)g,
      (__attribute__((address_space(3))) void*)l, 16, 0, 0);
}

union Pack8 { unsigned short us[8]; uint4 v; };

// --------------------------- elementwise cast ------------------------------
__global__ __launch_bounds__(256) void cast_f32_bf16(
    const float* __restrict__ in, unsigned short* __restrict__ out) {
  int i = (blockIdx.x * 256 + threadIdx.x) * 4;
  float4 v = *(const float4*)(in + i);
  ushort4 o;
  o.x = f2b(v.x); o.y = f2b(v.y); o.z = f2b(v.z); o.w = f2b(v.w);
  *(ushort4*)(out + i) = o;
}

// ------ fused cast+transpose of all 4 weights (saves 3 launch gaps) --------
// W[K=2048, N] f32 -> WT[N, 2048] bf16.  blockIdx.x partitions:
//   0..31 wq (N=2048) | 32..39 wk (512) | 40..47 wv (512) | 48..79 wo (2048)
// wq/wk/wv write into the contiguous [3072,2048] qkvT so the QKV GEMM merges.
__global__ __launch_bounds__(256) void cast_transpose_all(
    const float* __restrict__ wq, const float* __restrict__ wk,
    const float* __restrict__ wv, const float* __restrict__ wo,
    unsigned short* __restrict__ qkvT, unsigned short* __restrict__ woT) {
  __shared__ float tile[64][68];
  int bx = blockIdx.x;
  const float* W; unsigned short* WT; int N, nb;
  if (bx < 32)      { W = wq; WT = qkvT;                         N = 2048; nb = bx; }
  else if (bx < 40) { W = wk; WT = qkvT + (size_t)2048 * 2048;   N = 512;  nb = bx - 32; }
  else if (bx < 48) { W = wv; WT = qkvT + (size_t)2560 * 2048;   N = 512;  nb = bx - 40; }
  else              { W = wo; WT = woT;                          N = 2048; nb = bx - 48; }
  const int K = 2048;
  int n0 = nb * 64, k0 = blockIdx.y * 64;
  int t = threadIdx.x;
#pragma unroll
  for (int i = 0; i < 4; i++) {
    int c = t + 256 * i;              // 1024 chunks: 64 rows x 16 col-chunks(4)
    int r = c >> 4, cc = c & 15;
    float4 v = *(const float4*)(W + (size_t)(k0 + r) * N + n0 + cc * 4);
    tile[r][cc * 4 + 0] = v.x; tile[r][cc * 4 + 1] = v.y;
    tile[r][cc * 4 + 2] = v.z; tile[r][cc * 4 + 3] = v.w;
  }
  __syncthreads();
#pragma unroll
  for (int i = 0; i < 2; i++) {
    int c = t + 256 * i;              // 512 chunks: 64 n x 8 k-chunks(8)
    int n = c >> 3, kc = c & 7;
    Pack8 p;
#pragma unroll
    for (int j = 0; j < 8; j++) p.us[j] = f2b(tile[kc * 8 + j][n]);
    *(uint4*)(WT + (size_t)(n0 + n) * K + k0 + kc * 8) = p.v;
  }
}

// ------------------- GEMM: C[M,N] = A[M,K] @ Bt[N,K]^T ---------------------
// m97 tile (128x128, BK=32, 4 waves, 4x4 16x16 MFMA) + R5-attn pipeline:
// double-buffered LDS + counted s_waitcnt vmcnt(4) + raw s_barrier.
template <int OUT_BF16>
__global__ __launch_bounds__(256) void gemm_bt(
    const unsigned short* __restrict__ A, const unsigned short* __restrict__ Bt,
    void* __restrict__ C, int M, int N, int K) {
  __shared__ unsigned short As[2][128 * 32];   // lds-DMA layout, unpadded
  __shared__ unsigned short Bs[2][128 * 32];
  int t = threadIdx.x;
  int lane = t & 63, wave = t >> 6;
  int m0 = blockIdx.y * 128, n0 = blockIdx.x * 128;
  int wm = (wave >> 1) * 64, wn = (wave & 1) * 64;
  int fr = lane & 15, fq = lane >> 4;

  // staging map: wave w stages rows [w*32, w*32+32) of As and Bs (4 calls).
  int srow = wave * 32 + (lane >> 2);
  int scol = (lane & 3) * 8;
  const unsigned short* Ag = A + (size_t)(m0 + srow) * K + scol;
  const unsigned short* Bg = Bt + (size_t)(n0 + srow) * K + scol;

  auto stage = [&](int k0_, int bf) {
#pragma unroll
    for (int j = 0; j < 2; j++) {
      async_ld16(Ag + (size_t)j * 16 * K + k0_, &As[bf][wave * 1024 + j * 512]);
      async_ld16(Bg + (size_t)j * 16 * K + k0_, &Bs[bf][wave * 1024 + j * 512]);
    }
  };

  f32x4 acc[4][4];
#pragma unroll
  for (int mi = 0; mi < 4; mi++)
#pragma unroll
    for (int ni = 0; ni < 4; ni++) acc[mi][ni] = (f32x4){0.f, 0.f, 0.f, 0.f};

  stage(0, 0);
  int cur = 0;
  for (int k0 = 0; k0 < K; k0 += 32) {
    if (k0 + 32 < K) {
      stage(k0 + 32, cur ^ 1);           // 4 calls in flight across barrier
      asm volatile("s_waitcnt vmcnt(4)" ::: "memory");   // tile k0 landed
    } else {
      asm volatile("s_waitcnt vmcnt(0)" ::: "memory");
    }
    __builtin_amdgcn_s_barrier();
    asm volatile("" ::: "memory");
    bf16x8 a[4], b[4];
#pragma unroll
    for (int mi = 0; mi < 4; mi++)
      a[mi] = *(const bf16x8*)(&As[cur][(wm + 16 * mi + fr) * 32 + fq * 8]);
#pragma unroll
    for (int ni = 0; ni < 4; ni++)
      b[ni] = *(const bf16x8*)(&Bs[cur][(wn + 16 * ni + fr) * 32 + fq * 8]);
#pragma unroll
    for (int mi = 0; mi < 4; mi++)
#pragma unroll
      for (int ni = 0; ni < 4; ni++)
        acc[mi][ni] = __builtin_amdgcn_mfma_f32_16x16x32_bf16(
            a[mi], b[ni], acc[mi][ni], 0, 0, 0);
    asm volatile("s_waitcnt lgkmcnt(0)" ::: "memory");
    __builtin_amdgcn_s_barrier();        // all waves done reading buf[cur]
    asm volatile("" ::: "memory");
    cur ^= 1;
  }
#pragma unroll
  for (int mi = 0; mi < 4; mi++)
#pragma unroll
    for (int ni = 0; ni < 4; ni++)
#pragma unroll
      for (int r = 0; r < 4; r++) {
        int row = m0 + wm + 16 * mi + fq * 4 + r;
        int col = n0 + wn + 16 * ni + fr;
        float v = acc[mi][ni][r];
        if (OUT_BF16)
          ((unsigned short*)C)[(size_t)row * N + col] = f2b(v);
        else
          ((float*)C)[(size_t)row * N + col] = v;
      }
}

// ------------------------------ RoPE (in-place) ----------------------------
// Used for K only (Q rope is fused into attn's prologue).
template <int LOGH, int STRIDE, int SCALE_Q>
__global__ __launch_bounds__(256) void rope_inplace(unsigned short* __restrict__ X) {
  int p = blockIdx.x * 256 + threadIdx.x;
  int d = p & 63;
  int h = (p >> 6) & ((1 << LOGH) - 1);
  int row = p >> (6 + LOGH);
  int tpos = row & (T_SZ - 1);
  size_t base = (size_t)row * STRIDE + h * 128 + d;
  float u1 = b2f(X[base]), u2 = b2f(X[base + 64]);
  float inv = expf(-(float)d * 0.21586735246819178f);  // theta^(-d/64)
  float ang = (float)tpos * inv;
  float c = cosf(ang), s = sinf(ang);
  float o1 = u1 * c - u2 * s;
  float o2 = u2 * c + u1 * s;
  if (SCALE_Q) { o1 *= 0.08838834764831845f; o2 *= 0.08838834764831845f; }
  X[base]      = f2b(o1);
  X[base + 64] = f2b(o2);
}

// --------- V transpose: QKVb[., 2560 + kvh*128 + n] -> VT[b,kvh,n,t] -------
__global__ __launch_bounds__(256) void transpose_v(
    const unsigned short* __restrict__ V /* QKVb + 2560, row stride 3072 */,
    unsigned short* __restrict__ VT) {
  __shared__ unsigned short tile[64][72];
  int t0 = blockIdx.x * 64;
  int n0 = blockIdx.y * 64;        // within 128
  int bk = blockIdx.z;             // b*4 + kvh
  int b = bk >> 2, kvh = bk & 3;
  int t = threadIdx.x;
#pragma unroll
  for (int i = 0; i < 2; i++) {
    int c = t + 256 * i;           // 512 chunks: 64 t-rows x 8 n-chunks(8)
    int r = c >> 3, cc = c & 7;
    *(uint4*)&tile[r][cc * 8] = *(const uint4*)(
        V + (size_t)(b * T_SZ + t0 + r) * 3072 + kvh * 128 + n0 + cc * 8);
  }
  __syncthreads();
#pragma unroll
  for (int i = 0; i < 2; i++) {
    int c = t + 256 * i;           // 512 chunks: 64 n-rows x 8 t-chunks(8)
    int n = c >> 3, tc = c & 7;
    Pack8 p;
#pragma unroll
    for (int j = 0; j < 8; j++) p.us[j] = tile[tc * 8 + j][n];
    *(uint4*)(VT + ((size_t)bk * 128 + n0 + n) * T_SZ + t0 + tc * 8) = p.v;
  }
}

// -------------------------- flash attention --------------------------------
// S^T variant: compute S^T = K Q^T (A=K, B=Q); PV computes O^T via
// mfma(vf, pf) so all softmax state + O rows live on q-row = fr (lane-local).
//
// Round-9 (occupancy 2 -> 3 blocks/CU via T14 reg-staged K):
//  - K SINGLE LDS buffer + register staging (issue-early / write-late):
//    K(kt+1) global->reg at iter top (covered by the whole body), reg->LDS
//    ds_write in the dead window between the post-PV barrier and the next
//    top barrier (all Ks reads of iter kt completed at the post-PV barrier).
//  - V single DMA buffer restaged in the same window (as R5/R7).
//  - LDS = 16K (K) + 16K (V) + 19K (Ps) = 51 KB -> 3 blocks/CU = 24 waves/CU
//    (was 2 blocks; VGPR ~68 <= 85 = 512/6, __launch_bounds__(512,6)).
//  - vmcnt counting: V-DMA issued before K-reg loads; in-order retirement
//    makes vmcnt(2) = "V landed, K-regs in flight"; bottom vmcnt(0) waits
//    only the K-regs (issued a full body earlier).
//  - log2-domain softmax + defer-max (R8), Ps stride 76, qt pairing.
__global__ __launch_bounds__(512, 6) void attn(
    const unsigned short* __restrict__ Q,   // QKVb: [BT, 3072], Q in cols 0..2047
    const unsigned short* __restrict__ KV,  // QKVb + 2048: K cols, row stride 3072
    const unsigned short* __restrict__ VT,  // [B,4,128,T]
    unsigned short* __restrict__ O) {       // [BT, 2048]
  __shared__ unsigned short Ks[64 * 128];     // [kv][hd], slot-swizzled, single
  __shared__ unsigned short Vt[128 * 64];     // [hd][kv], slot-swizzled, single
  __shared__ unsigned short Ps[8][16 * 76];   // per-wave P: [q][kv], stride 76
  int qt = blockIdx.z ? blockIdx.x : 15 - blockIdx.x;
  int h = blockIdx.y, b = blockIdx.z;
  int kvh = h >> 2;
  int t = threadIdx.x, lane = t & 63, w = t >> 6;
  int fr = lane & 15, fq = lane >> 4;
  int rsw = fr & 7;                          // read-side swizzle: row&7 == fr&7

  // Q fragments direct from global (read exactly once per block)
  bf16x8 qf[4];
#pragma unroll
  for (int kk = 0; kk < 4; kk++)
    qf[kk] = *(const bf16x8*)(
        Q + (size_t)(b * T_SZ + qt * 128 + w * 16 + fr) * 3072 +
        h * 128 + kk * 32 + fq * 8);

  const unsigned short* Kg = KV + (size_t)b * T_SZ * 3072 + kvh * 128;
  const unsigned short* Vg = VT + (size_t)(b * 4 + kvh) * 128 * T_SZ;

  int k_lr = lane >> 4, k_ls = lane & 15;
  int v_lr = lane >> 3, v_ls = lane & 7;

  // K reg staging: same global addresses as the former DMA (pre-swizzled
  // source), dest = own 16B slot in the wave's rows (DMA-identical layout).
  uint4 kreg[2];
  auto load_k = [&](int kt_) {
#pragma unroll
    for (int j = 0; j < 2; j++) {
      int row = w * 8 + j * 4 + k_lr;       // 0..63
      kreg[j] = *(const uint4*)(
          Kg + (size_t)(kt_ * 64 + row) * 3072 + ((k_ls ^ (row & 7)) << 3));
    }
  };
  auto write_k = [&]() {
#pragma unroll
    for (int j = 0; j < 2; j++)
      *(uint4*)&Ks[(w * 8 + j * 4) * 128 + lane * 8] = kreg[j];
  };
  auto stage_v = [&](int kt_) {              // DMA, 2 calls/wave
#pragma unroll
    for (int j = 0; j < 2; j++) {
      int row = w * 16 + j * 8 + v_lr;      // 0..127 (hd)
      async_ld16(Vg + (size_t)row * T_SZ + kt_ * 64 + ((v_ls ^ (row & 7)) << 3),
                 &Vt[(w * 16 + j * 8) * 64]);
    }
  };

  load_k(0);

  // fused RoPE + scale on Q: scale = 1/sqrt(128) * log2(e)  (log2-domain
  // softmax).  d = kk*32 + fq*8 + j pairs with d+64 (held in qf[kk+2][j]).
  // Runs while kreg(0) loads are in flight.
  {
    const float QSCL = 0.08838834764831845f * 1.4426950408889634f;
    float tposf = (float)(qt * 128 + w * 16 + fr);
#pragma unroll
    for (int kk = 0; kk < 2; kk++)
#pragma unroll
      for (int j = 0; j < 8; j++) {
        int d = kk * 32 + (fq << 3) + j;
        float u1 = b2f((unsigned short)qf[kk][j]);
        float u2 = b2f((unsigned short)qf[kk + 2][j]);
        float inv = __expf(-(float)d * 0.21586735246819178f);  // theta^(-d/64)
        float ang = tposf * inv, c, s;
        __sincosf(ang, &s, &c);
        qf[kk][j]     = (short)f2b((u1 * c - u2 * s) * QSCL);
        qf[kk + 2][j] = (short)f2b((u2 * c + u1 * s) * QSCL);
      }
  }

  // prologue: K(0) regs -> LDS, V(0) DMA
  asm volatile("s_waitcnt vmcnt(0)" ::: "memory");
  write_k();
  asm volatile("s_waitcnt lgkmcnt(0)" ::: "memory");
  stage_v(0);

  f32x4 o[8];
#pragma unroll
  for (int i = 0; i < 8; i++) o[i] = (f32x4){0.f, 0.f, 0.f, 0.f};
  float mrow = -1e30f, lrow = 0.f;          // per-lane state; lrow is PARTIAL
  int qg = qt * 128 + w * 16 + fr;          // this lane's global q row
  int nkt = 2 * qt + 2;

  for (int kt = 0; kt < nkt; kt++) {
    if (kt + 1 < nkt) {
      load_k(kt + 1);                       // regs; in flight across barrier
      asm volatile("s_waitcnt vmcnt(2)" ::: "memory");  // V(kt) landed
    } else {
      asm volatile("s_waitcnt vmcnt(0)" ::: "memory");
    }
    __builtin_amdgcn_s_barrier();
    asm volatile("" ::: "memory");

    // S^T = K Q^T  (A=K: m=kv, B=Q: n=q).  Lane holds s[nn][r] for
    // q = w*16+fr, kv = kt*64 + nn*16 + fq*4 + r.
    f32x4 s[4];
    __builtin_amdgcn_s_setprio(1);
#pragma unroll
    for (int nn = 0; nn < 4; nn++) {
      s[nn] = (f32x4){0.f, 0.f, 0.f, 0.f};
#pragma unroll
      for (int kk = 0; kk < 4; kk++) {
        bf16x8 kf = *(const bf16x8*)(
            Ks + (nn * 16 + fr) * 128 + ((((kk << 2) + fq) ^ rsw) << 3));
        s[nn] = __builtin_amdgcn_mfma_f32_16x16x32_bf16(kf, qf[kk], s[nn], 0, 0, 0);
      }
    }
    __builtin_amdgcn_s_setprio(0);
    if (kt * 64 + 63 > qg) {                 // tile crosses causal boundary
#pragma unroll
      for (int nn = 0; nn < 4; nn++)
#pragma unroll
        for (int r = 0; r < 4; r++) {
          int kvg = kt * 64 + nn * 16 + fq * 4 + r;
          if (kvg > qg) s[nn][r] = -1e30f;
        }
    }
    // softmax (log2 domain): in-lane max tree, 2-step butterfly across fq
    f32x4 t4;
#pragma unroll
    for (int r = 0; r < 4; r++)
      t4[r] = fmaxf(fmaxf(s[0][r], s[1][r]), fmaxf(s[2][r], s[3][r]));
    float mx = fmaxf(fmaxf(t4[0], t4[1]), fmaxf(t4[2], t4[3]));
    mx = fmaxf(mx, __shfl_xor(mx, 16, 64));
    mx = fmaxf(mx, __shfl_xor(mx, 32, 64));
    // defer-max: only rescale when some row's max grew by >8 (P <= 2^8)
    if (__any(mx > mrow + 8.0f)) {
      float mnew = fmaxf(mrow, mx);
      float alpha = exp2_fast(mrow - mnew);
      lrow *= alpha;
#pragma unroll
      for (int nt = 0; nt < 8; nt++)
#pragma unroll
        for (int r = 0; r < 4; r++) o[nt][r] *= alpha;
      mrow = mnew;
    }
    float sum = 0.f;                         // partial: this lane's 16 values
#pragma unroll
    for (int nn = 0; nn < 4; nn++) {
      ushort4 pk;
      float p0 = exp2_fast(s[nn][0] - mrow); pk.x = f2b(p0);
      float p1 = exp2_fast(s[nn][1] - mrow); pk.y = f2b(p1);
      float p2 = exp2_fast(s[nn][2] - mrow); pk.z = f2b(p2);
      float p3 = exp2_fast(s[nn][3] - mrow); pk.w = f2b(p3);
      sum += (p0 + p1) + (p2 + p3);
      *(ushort4*)(Ps[w] + fr * 76 + nn * 16 + fq * 4) = pk;
    }
    lrow += sum;   // alpha already applied above when rescaled
    // O^T += V^T P^T  (A=vf: m=hd, B=pf: n=q).  o[nt][r] =
    // O[q=fr][hd = nt*16 + fq*4 + r] — same q-row as softmax state.
    __builtin_amdgcn_s_setprio(1);
#pragma unroll
    for (int kk = 0; kk < 2; kk++) {
      bf16x8 pf = *(const bf16x8*)(Ps[w] + fr * 76 + kk * 32 + fq * 8);
#pragma unroll
      for (int nt = 0; nt < 8; nt++) {
        bf16x8 vf = *(const bf16x8*)(
            Vt + (nt * 16 + fr) * 64 + ((((kk << 2) + fq) ^ rsw) << 3));
        o[nt] = __builtin_amdgcn_mfma_f32_16x16x32_bf16(vf, pf, o[nt], 0, 0, 0);
      }
    }
    __builtin_amdgcn_s_setprio(0);
    asm volatile("s_waitcnt lgkmcnt(0)" ::: "memory");
    __builtin_amdgcn_s_barrier();            // all waves done reading Ks, Vt
    asm volatile("" ::: "memory");
    if (kt + 1 < nkt) {
      // dead window: Ks fully consumed; write K(kt+1) regs + restage V.
      asm volatile("s_waitcnt vmcnt(0)" ::: "memory");   // kreg arrived
      write_k();
      asm volatile("s_waitcnt lgkmcnt(0)" ::: "memory"); // writes done pre-barrier
      stage_v(kt + 1);                       // lands by next top vmcnt(2)
    }
  }
  // epilogue: reduce partial l across the 4 fq-lanes of this q-row, then
  // vectorized stores: lane covers cols nt*16 + fq*4 + 0..3 of row q=fr.
  float lsum = lrow;
  lsum += __shfl_xor(lsum, 16, 64);
  lsum += __shfl_xor(lsum, 32, 64);
  float linv = 1.f / lsum;
  int rowg = b * T_SZ + qt * 128 + w * 16 + fr;
#pragma unroll
  for (int nt = 0; nt < 8; nt++) {
    ushort4 ov;
    ov.x = f2b(o[nt][0] * linv);
    ov.y = f2b(o[nt][1] * linv);
    ov.z = f2b(o[nt][2] * linv);
    ov.w = f2b(o[nt][3] * linv);
    *(ushort4*)(O + (size_t)rowg * 2048 + h * 128 + nt * 16 + fq * 4) = ov;
  }
}

// ---------------------------------------------------------------------------
extern "C" void kernel_launch(void* const* d_in, const int* in_sizes, int n_in,
                              void* d_out, int out_size, void* d_ws, size_t ws_size,
                              hipStream_t stream) {
  const float* x  = (const float*)d_in[0];
  const float* wq = (const float*)d_in[1];
  const float* wk = (const float*)d_in[2];
  const float* wv = (const float*)d_in[3];
  const float* wo = (const float*)d_in[4];
  float* out = (float*)d_out;

  unsigned short* xb   = (unsigned short*)d_ws;             // [4096,2048]
  unsigned short* wqT  = xb   + (size_t)4096 * 2048;        // [3072,2048]: wq|wk|wv transposed
  unsigned short* woT  = wqT  + (size_t)3072 * 2048;        // [2048,2048]
  unsigned short* QKVb = woT  + (size_t)2048 * 2048;        // [4096,3072]: Q | K | V
  unsigned short* VTb  = QKVb + (size_t)4096 * 3072;        // [2,4,128,2048]
  unsigned short* AOb  = VTb  + (size_t)4096 * 512;         // [4096,2048]

  cast_f32_bf16<<<8192, 256, 0, stream>>>(x, xb);
  cast_transpose_all<<<dim3(80, 32), 256, 0, stream>>>(wq, wk, wv, wo, wqT, woT);

  // merged QKV projection: [4096,2048] @ [3072,2048]^T -> [4096,3072]
  gemm_bt<1><<<dim3(24, 32), 256, 0, stream>>>(xb, wqT, QKVb, 4096, 3072, 2048);

  rope_inplace<2, 3072, 0><<<4096, 256, 0, stream>>>(QKVb + 2048); // K only
  transpose_v<<<dim3(32, 2, 8), 256, 0, stream>>>(QKVb + 2560, VTb);

  attn<<<dim3(16, 16, 2), 512, 0, stream>>>(QKVb, QKVb + 2048, VTb, AOb);

  gemm_bt<0><<<dim3(16, 32), 256, 0, stream>>>(AOb, woT, (void*)out, 4096, 2048, 2048);
}

// Round 10
// 325.680 us; speedup vs baseline: 1.3172x; 1.3172x over previous
//
#include <hip/hip_runtime.h>

// ---------------------------------------------------------------------------
// EagerAttention: x[B,T,D] -> QKV proj -> RoPE -> causal GQA attention -> out proj
// B=2 T=2048 D=2048 NH=16 NKV=4 HD=128, fp32 in/out, bf16 MFMA internally.
// ---------------------------------------------------------------------------

#define T_SZ 2048
#define D_SZ 2048
#define BT   4096   // B*T

typedef __attribute__((ext_vector_type(8))) short bf16x8;
typedef __attribute__((ext_vector_type(4))) float f32x4;

__device__ __forceinline__ unsigned short f2b(float f) {
  unsigned u = __float_as_uint(f);
  u = (u + 0x7fffu + ((u >> 16) & 1u)) >> 16;   // RNE
  return (unsigned short)u;
}
__device__ __forceinline__ float b2f(unsigned short h) {
  return __uint_as_float(((unsigned)h) << 16);
}

#if __has_builtin(__builtin_amdgcn_exp2f)
__device__ __forceinline__ float exp2_fast(float x) { return __builtin_amdgcn_exp2f(x); }
#else
__device__ __forceinline__ float exp2_fast(float x) {
  float r; asm("v_exp_f32 %0, %1" : "=v"(r) : "v"(x)); return r;
}
#endif

// async global->LDS 16B/lane: dest is wave-uniform base + lane*16
__device__ __forceinline__ void async_ld16(const void* g, void* l) {
  __builtin_amdgcn_global_load_lds(
      (const __attribute__((address_space(1))) void*)g,
      (__attribute__((address_space(3))) void*)l, 16, 0, 0);
}

union Pack8 { unsigned short us[8]; uint4 v; };

// --------------------------- elementwise cast ------------------------------
__global__ __launch_bounds__(256) void cast_f32_bf16(
    const float* __restrict__ in, unsigned short* __restrict__ out) {
  int i = (blockIdx.x * 256 + threadIdx.x) * 4;
  float4 v = *(const float4*)(in + i);
  ushort4 o;
  o.x = f2b(v.x); o.y = f2b(v.y); o.z = f2b(v.z); o.w = f2b(v.w);
  *(ushort4*)(out + i) = o;
}

// ------ fused cast+transpose of all 4 weights (saves 3 launch gaps) --------
// W[K=2048, N] f32 -> WT[N, 2048] bf16.  blockIdx.x partitions:
//   0..31 wq (N=2048) | 32..39 wk (512) | 40..47 wv (512) | 48..79 wo (2048)
// wq/wk/wv write into the contiguous [3072,2048] qkvT so the QKV GEMM merges.
__global__ __launch_bounds__(256) void cast_transpose_all(
    const float* __restrict__ wq, const float* __restrict__ wk,
    const float* __restrict__ wv, const float* __restrict__ wo,
    unsigned short* __restrict__ qkvT, unsigned short* __restrict__ woT) {
  __shared__ float tile[64][68];
  int bx = blockIdx.x;
  const float* W; unsigned short* WT; int N, nb;
  if (bx < 32)      { W = wq; WT = qkvT;                         N = 2048; nb = bx; }
  else if (bx < 40) { W = wk; WT = qkvT + (size_t)2048 * 2048;   N = 512;  nb = bx - 32; }
  else if (bx < 48) { W = wv; WT = qkvT + (size_t)2560 * 2048;   N = 512;  nb = bx - 40; }
  else              { W = wo; WT = woT;                          N = 2048; nb = bx - 48; }
  const int K = 2048;
  int n0 = nb * 64, k0 = blockIdx.y * 64;
  int t = threadIdx.x;
#pragma unroll
  for (int i = 0; i < 4; i++) {
    int c = t + 256 * i;              // 1024 chunks: 64 rows x 16 col-chunks(4)
    int r = c >> 4, cc = c & 15;
    float4 v = *(const float4*)(W + (size_t)(k0 + r) * N + n0 + cc * 4);
    tile[r][cc * 4 + 0] = v.x; tile[r][cc * 4 + 1] = v.y;
    tile[r][cc * 4 + 2] = v.z; tile[r][cc * 4 + 3] = v.w;
  }
  __syncthreads();
#pragma unroll
  for (int i = 0; i < 2; i++) {
    int c = t + 256 * i;              // 512 chunks: 64 n x 8 k-chunks(8)
    int n = c >> 3, kc = c & 7;
    Pack8 p;
#pragma unroll
    for (int j = 0; j < 8; j++) p.us[j] = f2b(tile[kc * 8 + j][n]);
    *(uint4*)(WT + (size_t)(n0 + n) * K + k0 + kc * 8) = p.v;
  }
}

// ------------------- GEMM: C[M,N] = A[M,K] @ Bt[N,K]^T ---------------------
// m97 tile (128x128, BK=32, 4 waves, 4x4 16x16 MFMA) + R5-attn pipeline:
// double-buffered LDS + counted s_waitcnt vmcnt(4) + raw s_barrier.
template <int OUT_BF16>
__global__ __launch_bounds__(256) void gemm_bt(
    const unsigned short* __restrict__ A, const unsigned short* __restrict__ Bt,
    void* __restrict__ C, int M, int N, int K) {
  __shared__ unsigned short As[2][128 * 32];   // lds-DMA layout, unpadded
  __shared__ unsigned short Bs[2][128 * 32];
  int t = threadIdx.x;
  int lane = t & 63, wave = t >> 6;
  int m0 = blockIdx.y * 128, n0 = blockIdx.x * 128;
  int wm = (wave >> 1) * 64, wn = (wave & 1) * 64;
  int fr = lane & 15, fq = lane >> 4;

  // staging map: wave w stages rows [w*32, w*32+32) of As and Bs (4 calls).
  int srow = wave * 32 + (lane >> 2);
  int scol = (lane & 3) * 8;
  const unsigned short* Ag = A + (size_t)(m0 + srow) * K + scol;
  const unsigned short* Bg = Bt + (size_t)(n0 + srow) * K + scol;

  auto stage = [&](int k0_, int bf) {
#pragma unroll
    for (int j = 0; j < 2; j++) {
      async_ld16(Ag + (size_t)j * 16 * K + k0_, &As[bf][wave * 1024 + j * 512]);
      async_ld16(Bg + (size_t)j * 16 * K + k0_, &Bs[bf][wave * 1024 + j * 512]);
    }
  };

  f32x4 acc[4][4];
#pragma unroll
  for (int mi = 0; mi < 4; mi++)
#pragma unroll
    for (int ni = 0; ni < 4; ni++) acc[mi][ni] = (f32x4){0.f, 0.f, 0.f, 0.f};

  stage(0, 0);
  int cur = 0;
  for (int k0 = 0; k0 < K; k0 += 32) {
    if (k0 + 32 < K) {
      stage(k0 + 32, cur ^ 1);           // 4 calls in flight across barrier
      asm volatile("s_waitcnt vmcnt(4)" ::: "memory");   // tile k0 landed
    } else {
      asm volatile("s_waitcnt vmcnt(0)" ::: "memory");
    }
    __builtin_amdgcn_s_barrier();
    asm volatile("" ::: "memory");
    bf16x8 a[4], b[4];
#pragma unroll
    for (int mi = 0; mi < 4; mi++)
      a[mi] = *(const bf16x8*)(&As[cur][(wm + 16 * mi + fr) * 32 + fq * 8]);
#pragma unroll
    for (int ni = 0; ni < 4; ni++)
      b[ni] = *(const bf16x8*)(&Bs[cur][(wn + 16 * ni + fr) * 32 + fq * 8]);
#pragma unroll
    for (int mi = 0; mi < 4; mi++)
#pragma unroll
      for (int ni = 0; ni < 4; ni++)
        acc[mi][ni] = __builtin_amdgcn_mfma_f32_16x16x32_bf16(
            a[mi], b[ni], acc[mi][ni], 0, 0, 0);
    asm volatile("s_waitcnt lgkmcnt(0)" ::: "memory");
    __builtin_amdgcn_s_barrier();        // all waves done reading buf[cur]
    asm volatile("" ::: "memory");
    cur ^= 1;
  }
#pragma unroll
  for (int mi = 0; mi < 4; mi++)
#pragma unroll
    for (int ni = 0; ni < 4; ni++)
#pragma unroll
      for (int r = 0; r < 4; r++) {
        int row = m0 + wm + 16 * mi + fq * 4 + r;
        int col = n0 + wn + 16 * ni + fr;
        float v = acc[mi][ni][r];
        if (OUT_BF16)
          ((unsigned short*)C)[(size_t)row * N + col] = f2b(v);
        else
          ((float*)C)[(size_t)row * N + col] = v;
      }
}

// ------------------------------ RoPE (in-place) ----------------------------
// Used for K only (Q rope is fused into attn's prologue).
template <int LOGH, int STRIDE, int SCALE_Q>
__global__ __launch_bounds__(256) void rope_inplace(unsigned short* __restrict__ X) {
  int p = blockIdx.x * 256 + threadIdx.x;
  int d = p & 63;
  int h = (p >> 6) & ((1 << LOGH) - 1);
  int row = p >> (6 + LOGH);
  int tpos = row & (T_SZ - 1);
  size_t base = (size_t)row * STRIDE + h * 128 + d;
  float u1 = b2f(X[base]), u2 = b2f(X[base + 64]);
  float inv = expf(-(float)d * 0.21586735246819178f);  // theta^(-d/64)
  float ang = (float)tpos * inv;
  float c = cosf(ang), s = sinf(ang);
  float o1 = u1 * c - u2 * s;
  float o2 = u2 * c + u1 * s;
  if (SCALE_Q) { o1 *= 0.08838834764831845f; o2 *= 0.08838834764831845f; }
  X[base]      = f2b(o1);
  X[base + 64] = f2b(o2);
}

// --------- V transpose: QKVb[., 2560 + kvh*128 + n] -> VT[b,kvh,n,t] -------
__global__ __launch_bounds__(256) void transpose_v(
    const unsigned short* __restrict__ V /* QKVb + 2560, row stride 3072 */,
    unsigned short* __restrict__ VT) {
  __shared__ unsigned short tile[64][72];
  int t0 = blockIdx.x * 64;
  int n0 = blockIdx.y * 64;        // within 128
  int bk = blockIdx.z;             // b*4 + kvh
  int b = bk >> 2, kvh = bk & 3;
  int t = threadIdx.x;
#pragma unroll
  for (int i = 0; i < 2; i++) {
    int c = t + 256 * i;           // 512 chunks: 64 t-rows x 8 n-chunks(8)
    int r = c >> 3, cc = c & 7;
    *(uint4*)&tile[r][cc * 8] = *(const uint4*)(
        V + (size_t)(b * T_SZ + t0 + r) * 3072 + kvh * 128 + n0 + cc * 8);
  }
  __syncthreads();
#pragma unroll
  for (int i = 0; i < 2; i++) {
    int c = t + 256 * i;           // 512 chunks: 64 n-rows x 8 t-chunks(8)
    int n = c >> 3, tc = c & 7;
    Pack8 p;
#pragma unroll
    for (int j = 0; j < 8; j++) p.us[j] = tile[tc * 8 + j][n];
    *(uint4*)(VT + ((size_t)bk * 128 + n0 + n) * T_SZ + t0 + tc * 8) = p.v;
  }
}

// -------------------------- flash attention --------------------------------
// S^T variant: compute S^T = K Q^T (A=K, B=Q); PV computes O^T via
// mfma(vf, pf) so all softmax state + O rows live on q-row = fr (lane-local).
//
// Round-10 (= R9 minus the launch-bounds register squeeze):
//  R9's __launch_bounds__(512, 6) forced VGPR 40 -> accumulator spill to
//  scratch (FETCH/WRITE 235 MB each, attn 203 us).  Natural allocation of
//  this body is ~68 VGPR <= 85 (= 512/6), so 3 blocks/CU comes from the
//  51 KB LDS budget alone; plain __launch_bounds__(512) lets the allocator
//  breathe.  Structure unchanged from R9:
//  - K single LDS buffer + reg staging (load at iter top, ds_write in the
//    dead window after the post-PV barrier).
//  - V single DMA buffer restaged in the same window.
//  - LDS = 16K (K) + 16K (V) + 19K (Ps) = 51 KB -> 3 blocks/CU.
//  - vmcnt(2) = "V landed, K-regs in flight" (in-order retirement).
//  - log2-domain softmax + defer-max, Ps stride 76, qt pairing.
__global__ __launch_bounds__(512) void attn(
    const unsigned short* __restrict__ Q,   // QKVb: [BT, 3072], Q in cols 0..2047
    const unsigned short* __restrict__ KV,  // QKVb + 2048: K cols, row stride 3072
    const unsigned short* __restrict__ VT,  // [B,4,128,T]
    unsigned short* __restrict__ O) {       // [BT, 2048]
  __shared__ unsigned short Ks[64 * 128];     // [kv][hd], slot-swizzled, single
  __shared__ unsigned short Vt[128 * 64];     // [hd][kv], slot-swizzled, single
  __shared__ unsigned short Ps[8][16 * 76];   // per-wave P: [q][kv], stride 76
  int qt = blockIdx.z ? blockIdx.x : 15 - blockIdx.x;
  int h = blockIdx.y, b = blockIdx.z;
  int kvh = h >> 2;
  int t = threadIdx.x, lane = t & 63, w = t >> 6;
  int fr = lane & 15, fq = lane >> 4;
  int rsw = fr & 7;                          // read-side swizzle: row&7 == fr&7

  // Q fragments direct from global (read exactly once per block)
  bf16x8 qf[4];
#pragma unroll
  for (int kk = 0; kk < 4; kk++)
    qf[kk] = *(const bf16x8*)(
        Q + (size_t)(b * T_SZ + qt * 128 + w * 16 + fr) * 3072 +
        h * 128 + kk * 32 + fq * 8);

  const unsigned short* Kg = KV + (size_t)b * T_SZ * 3072 + kvh * 128;
  const unsigned short* Vg = VT + (size_t)(b * 4 + kvh) * 128 * T_SZ;

  int k_lr = lane >> 4, k_ls = lane & 15;
  int v_lr = lane >> 3, v_ls = lane & 7;

  // K reg staging: same global addresses as the former DMA (pre-swizzled
  // source), dest = own 16B slot in the wave's rows (DMA-identical layout).
  uint4 kreg[2];
  auto load_k = [&](int kt_) {
#pragma unroll
    for (int j = 0; j < 2; j++) {
      int row = w * 8 + j * 4 + k_lr;       // 0..63
      kreg[j] = *(const uint4*)(
          Kg + (size_t)(kt_ * 64 + row) * 3072 + ((k_ls ^ (row & 7)) << 3));
    }
  };
  auto write_k = [&]() {
#pragma unroll
    for (int j = 0; j < 2; j++)
      *(uint4*)&Ks[(w * 8 + j * 4) * 128 + lane * 8] = kreg[j];
  };
  auto stage_v = [&](int kt_) {              // DMA, 2 calls/wave
#pragma unroll
    for (int j = 0; j < 2; j++) {
      int row = w * 16 + j * 8 + v_lr;      // 0..127 (hd)
      async_ld16(Vg + (size_t)row * T_SZ + kt_ * 64 + ((v_ls ^ (row & 7)) << 3),
                 &Vt[(w * 16 + j * 8) * 64]);
    }
  };

  load_k(0);

  // fused RoPE + scale on Q: scale = 1/sqrt(128) * log2(e)  (log2-domain
  // softmax).  d = kk*32 + fq*8 + j pairs with d+64 (held in qf[kk+2][j]).
  // Runs while kreg(0) loads are in flight.
  {
    const float QSCL = 0.08838834764831845f * 1.4426950408889634f;
    float tposf = (float)(qt * 128 + w * 16 + fr);
#pragma unroll
    for (int kk = 0; kk < 2; kk++)
#pragma unroll
      for (int j = 0; j < 8; j++) {
        int d = kk * 32 + (fq << 3) + j;
        float u1 = b2f((unsigned short)qf[kk][j]);
        float u2 = b2f((unsigned short)qf[kk + 2][j]);
        float inv = __expf(-(float)d * 0.21586735246819178f);  // theta^(-d/64)
        float ang = tposf * inv, c, s;
        __sincosf(ang, &s, &c);
        qf[kk][j]     = (short)f2b((u1 * c - u2 * s) * QSCL);
        qf[kk + 2][j] = (short)f2b((u2 * c + u1 * s) * QSCL);
      }
  }

  // prologue: K(0) regs -> LDS, V(0) DMA
  asm volatile("s_waitcnt vmcnt(0)" ::: "memory");
  write_k();
  asm volatile("s_waitcnt lgkmcnt(0)" ::: "memory");
  stage_v(0);

  f32x4 o[8];
#pragma unroll
  for (int i = 0; i < 8; i++) o[i] = (f32x4){0.f, 0.f, 0.f, 0.f};
  float mrow = -1e30f, lrow = 0.f;          // per-lane state; lrow is PARTIAL
  int qg = qt * 128 + w * 16 + fr;          // this lane's global q row
  int nkt = 2 * qt + 2;

  for (int kt = 0; kt < nkt; kt++) {
    if (kt + 1 < nkt) {
      load_k(kt + 1);                       // regs; in flight across barrier
      asm volatile("s_waitcnt vmcnt(2)" ::: "memory");  // V(kt) landed
    } else {
      asm volatile("s_waitcnt vmcnt(0)" ::: "memory");
    }
    __builtin_amdgcn_s_barrier();
    asm volatile("" ::: "memory");

    // S^T = K Q^T  (A=K: m=kv, B=Q: n=q).  Lane holds s[nn][r] for
    // q = w*16+fr, kv = kt*64 + nn*16 + fq*4 + r.
    f32x4 s[4];
    __builtin_amdgcn_s_setprio(1);
#pragma unroll
    for (int nn = 0; nn < 4; nn++) {
      s[nn] = (f32x4){0.f, 0.f, 0.f, 0.f};
#pragma unroll
      for (int kk = 0; kk < 4; kk++) {
        bf16x8 kf = *(const bf16x8*)(
            Ks + (nn * 16 + fr) * 128 + ((((kk << 2) + fq) ^ rsw) << 3));
        s[nn] = __builtin_amdgcn_mfma_f32_16x16x32_bf16(kf, qf[kk], s[nn], 0, 0, 0);
      }
    }
    __builtin_amdgcn_s_setprio(0);
    if (kt * 64 + 63 > qg) {                 // tile crosses causal boundary
#pragma unroll
      for (int nn = 0; nn < 4; nn++)
#pragma unroll
        for (int r = 0; r < 4; r++) {
          int kvg = kt * 64 + nn * 16 + fq * 4 + r;
          if (kvg > qg) s[nn][r] = -1e30f;
        }
    }
    // softmax (log2 domain): in-lane max tree, 2-step butterfly across fq
    f32x4 t4;
#pragma unroll
    for (int r = 0; r < 4; r++)
      t4[r] = fmaxf(fmaxf(s[0][r], s[1][r]), fmaxf(s[2][r], s[3][r]));
    float mx = fmaxf(fmaxf(t4[0], t4[1]), fmaxf(t4[2], t4[3]));
    mx = fmaxf(mx, __shfl_xor(mx, 16, 64));
    mx = fmaxf(mx, __shfl_xor(mx, 32, 64));
    // defer-max: only rescale when some row's max grew by >8 (P <= 2^8)
    if (__any(mx > mrow + 8.0f)) {
      float mnew = fmaxf(mrow, mx);
      float alpha = exp2_fast(mrow - mnew);
      lrow *= alpha;
#pragma unroll
      for (int nt = 0; nt < 8; nt++)
#pragma unroll
        for (int r = 0; r < 4; r++) o[nt][r] *= alpha;
      mrow = mnew;
    }
    float sum = 0.f;                         // partial: this lane's 16 values
#pragma unroll
    for (int nn = 0; nn < 4; nn++) {
      ushort4 pk;
      float p0 = exp2_fast(s[nn][0] - mrow); pk.x = f2b(p0);
      float p1 = exp2_fast(s[nn][1] - mrow); pk.y = f2b(p1);
      float p2 = exp2_fast(s[nn][2] - mrow); pk.z = f2b(p2);
      float p3 = exp2_fast(s[nn][3] - mrow); pk.w = f2b(p3);
      sum += (p0 + p1) + (p2 + p3);
      *(ushort4*)(Ps[w] + fr * 76 + nn * 16 + fq * 4) = pk;
    }
    lrow += sum;   // alpha already applied above when rescaled
    // O^T += V^T P^T  (A=vf: m=hd, B=pf: n=q).  o[nt][r] =
    // O[q=fr][hd = nt*16 + fq*4 + r] — same q-row as softmax state.
    __builtin_amdgcn_s_setprio(1);
#pragma unroll
    for (int kk = 0; kk < 2; kk++) {
      bf16x8 pf = *(const bf16x8*)(Ps[w] + fr * 76 + kk * 32 + fq * 8);
#pragma unroll
      for (int nt = 0; nt < 8; nt++) {
        bf16x8 vf = *(const bf16x8*)(
            Vt + (nt * 16 + fr) * 64 + ((((kk << 2) + fq) ^ rsw) << 3));
        o[nt] = __builtin_amdgcn_mfma_f32_16x16x32_bf16(vf, pf, o[nt], 0, 0, 0);
      }
    }
    __builtin_amdgcn_s_setprio(0);
    asm volatile("s_waitcnt lgkmcnt(0)" ::: "memory");
    __builtin_amdgcn_s_barrier();            // all waves done reading Ks, Vt
    asm volatile("" ::: "memory");
    if (kt + 1 < nkt) {
      // dead window: Ks fully consumed; write K(kt+1) regs + restage V.
      asm volatile("s_waitcnt vmcnt(0)" ::: "memory");   // kreg arrived
      write_k();
      asm volatile("s_waitcnt lgkmcnt(0)" ::: "memory"); // writes done pre-barrier
      stage_v(kt + 1);                       // lands by next top vmcnt(2)
    }
  }
  // epilogue: reduce partial l across the 4 fq-lanes of this q-row, then
  // vectorized stores: lane covers cols nt*16 + fq*4 + 0..3 of row q=fr.
  float lsum = lrow;
  lsum += __shfl_xor(lsum, 16, 64);
  lsum += __shfl_xor(lsum, 32, 64);
  float linv = 1.f / lsum;
  int rowg = b * T_SZ + qt * 128 + w * 16 + fr;
#pragma unroll
  for (int nt = 0; nt < 8; nt++) {
    ushort4 ov;
    ov.x = f2b(o[nt][0] * linv);
    ov.y = f2b(o[nt][1] * linv);
    ov.z = f2b(o[nt][2] * linv);
    ov.w = f2b(o[nt][3] * linv);
    *(ushort4*)(O + (size_t)rowg * 2048 + h * 128 + nt * 16 + fq * 4) = ov;
  }
}

// ---------------------------------------------------------------------------
extern "C" void kernel_launch(void* const* d_in, const int* in_sizes, int n_in,
                              void* d_out, int out_size, void* d_ws, size_t ws_size,
                              hipStream_t stream) {
  const float* x  = (const float*)d_in[0];
  const float* wq = (const float*)d_in[1];
  const float* wk = (const float*)d_in[2];
  const float* wv = (const float*)d_in[3];
  const float* wo = (const float*)d_in[4];
  float* out = (float*)d_out;

  unsigned short* xb   = (unsigned short*)d_ws;             // [4096,2048]
  unsigned short* wqT  = xb   + (size_t)4096 * 2048;        // [3072,2048]: wq|wk|wv transposed
  unsigned short* woT  = wqT  + (size_t)3072 * 2048;        // [2048,2048]
  unsigned short* QKVb = woT  + (size_t)2048 * 2048;        // [4096,3072]: Q | K | V
  unsigned short* VTb  = QKVb + (size_t)4096 * 3072;        // [2,4,128,2048]
  unsigned short* AOb  = VTb  + (size_t)4096 * 512;         // [4096,2048]

  cast_f32_bf16<<<8192, 256, 0, stream>>>(x, xb);
  cast_transpose_all<<<dim3(80, 32), 256, 0, stream>>>(wq, wk, wv, wo, wqT, woT);

  // merged QKV projection: [4096,2048] @ [3072,2048]^T -> [4096,3072]
  gemm_bt<1><<<dim3(24, 32), 256, 0, stream>>>(xb, wqT, QKVb, 4096, 3072, 2048);

  rope_inplace<2, 3072, 0><<<4096, 256, 0, stream>>>(QKVb + 2048); // K only
  transpose_v<<<dim3(32, 2, 8), 256, 0, stream>>>(QKVb + 2560, VTb);

  attn<<<dim3(16, 16, 2), 512, 0, stream>>>(QKVb, QKVb + 2048, VTb, AOb);

  gemm_bt<0><<<dim3(16, 32), 256, 0, stream>>>(AOb, woT, (void*)out, 4096, 2048, 2048);
}

// Round 11
// 303.199 us; speedup vs baseline: 1.4148x; 1.0741x over previous
//
#include <hip/hip_runtime.h>

// ---------------------------------------------------------------------------
// EagerAttention: x[B,T,D] -> QKV proj -> RoPE -> causal GQA attention -> out proj
// B=2 T=2048 D=2048 NH=16 NKV=4 HD=128, fp32 in/out, bf16 MFMA internally.
// ---------------------------------------------------------------------------

#define T_SZ 2048
#define D_SZ 2048
#define BT   4096   // B*T

typedef __attribute__((ext_vector_type(8))) short bf16x8;
typedef __attribute__((ext_vector_type(4))) float f32x4;

__device__ __forceinline__ unsigned short f2b(float f) {
  unsigned u = __float_as_uint(f);
  u = (u + 0x7fffu + ((u >> 16) & 1u)) >> 16;   // RNE
  return (unsigned short)u;
}
__device__ __forceinline__ float b2f(unsigned short h) {
  return __uint_as_float(((unsigned)h) << 16);
}

#if __has_builtin(__builtin_amdgcn_exp2f)
__device__ __forceinline__ float exp2_fast(float x) { return __builtin_amdgcn_exp2f(x); }
#else
__device__ __forceinline__ float exp2_fast(float x) {
  float r; asm("v_exp_f32 %0, %1" : "=v"(r) : "v"(x)); return r;
}
#endif

// async global->LDS 16B/lane: dest is wave-uniform base + lane*16
__device__ __forceinline__ void async_ld16(const void* g, void* l) {
  __builtin_amdgcn_global_load_lds(
      (const __attribute__((address_space(1))) void*)g,
      (__attribute__((address_space(3))) void*)l, 16, 0, 0);
}

union Pack8 { unsigned short us[8]; uint4 v; };

// --------------------------- elementwise cast ------------------------------
__global__ __launch_bounds__(256) void cast_f32_bf16(
    const float* __restrict__ in, unsigned short* __restrict__ out) {
  int i = (blockIdx.x * 256 + threadIdx.x) * 4;
  float4 v = *(const float4*)(in + i);
  ushort4 o;
  o.x = f2b(v.x); o.y = f2b(v.y); o.z = f2b(v.z); o.w = f2b(v.w);
  *(ushort4*)(out + i) = o;
}

// ------ fused cast+transpose of all 4 weights (saves 3 launch gaps) --------
// W[K=2048, N] f32 -> WT[N, 2048] bf16.  blockIdx.x partitions:
//   0..31 wq (N=2048) | 32..39 wk (512) | 40..47 wv (512) | 48..79 wo (2048)
// wq/wk/wv write into the contiguous [3072,2048] qkvT so the QKV GEMM merges.
__global__ __launch_bounds__(256) void cast_transpose_all(
    const float* __restrict__ wq, const float* __restrict__ wk,
    const float* __restrict__ wv, const float* __restrict__ wo,
    unsigned short* __restrict__ qkvT, unsigned short* __restrict__ woT) {
  __shared__ float tile[64][68];
  int bx = blockIdx.x;
  const float* W; unsigned short* WT; int N, nb;
  if (bx < 32)      { W = wq; WT = qkvT;                         N = 2048; nb = bx; }
  else if (bx < 40) { W = wk; WT = qkvT + (size_t)2048 * 2048;   N = 512;  nb = bx - 32; }
  else if (bx < 48) { W = wv; WT = qkvT + (size_t)2560 * 2048;   N = 512;  nb = bx - 40; }
  else              { W = wo; WT = woT;                          N = 2048; nb = bx - 48; }
  const int K = 2048;
  int n0 = nb * 64, k0 = blockIdx.y * 64;
  int t = threadIdx.x;
#pragma unroll
  for (int i = 0; i < 4; i++) {
    int c = t + 256 * i;              // 1024 chunks: 64 rows x 16 col-chunks(4)
    int r = c >> 4, cc = c & 15;
    float4 v = *(const float4*)(W + (size_t)(k0 + r) * N + n0 + cc * 4);
    tile[r][cc * 4 + 0] = v.x; tile[r][cc * 4 + 1] = v.y;
    tile[r][cc * 4 + 2] = v.z; tile[r][cc * 4 + 3] = v.w;
  }
  __syncthreads();
#pragma unroll
  for (int i = 0; i < 2; i++) {
    int c = t + 256 * i;              // 512 chunks: 64 n x 8 k-chunks(8)
    int n = c >> 3, kc = c & 7;
    Pack8 p;
#pragma unroll
    for (int j = 0; j < 8; j++) p.us[j] = f2b(tile[kc * 8 + j][n]);
    *(uint4*)(WT + (size_t)(n0 + n) * K + k0 + kc * 8) = p.v;
  }
}

// ------------------- GEMM: C[M,N] = A[M,K] @ Bt[N,K]^T ---------------------
// m97 tile (128x128, BK=32, 4 waves, 4x4 16x16 MFMA) + counted-vmcnt pipeline,
// now 3-DEEP: triple-buffered LDS, stage(k+2) at top, s_waitcnt vmcnt(8) —
// staging gets TWO iterations of latency cover (L3 ~500cyc / HBM ~900cyc)
// instead of one.  Buffer (cur+2)%3 was last read two iters ago (drained at
// that iteration's lgkmcnt(0)+barrier).  LDS 48 KB -> still 3 blocks/CU
// (VGPR is the occupancy limiter for this kernel).
template <int OUT_BF16>
__global__ __launch_bounds__(256) void gemm_bt(
    const unsigned short* __restrict__ A, const unsigned short* __restrict__ Bt,
    void* __restrict__ C, int M, int N, int K) {
  __shared__ unsigned short As[3][128 * 32];   // lds-DMA layout, unpadded
  __shared__ unsigned short Bs[3][128 * 32];
  int t = threadIdx.x;
  int lane = t & 63, wave = t >> 6;
  int m0 = blockIdx.y * 128, n0 = blockIdx.x * 128;
  int wm = (wave >> 1) * 64, wn = (wave & 1) * 64;
  int fr = lane & 15, fq = lane >> 4;

  // staging map: wave w stages rows [w*32, w*32+32) of As and Bs (4 calls).
  int srow = wave * 32 + (lane >> 2);
  int scol = (lane & 3) * 8;
  const unsigned short* Ag = A + (size_t)(m0 + srow) * K + scol;
  const unsigned short* Bg = Bt + (size_t)(n0 + srow) * K + scol;

  auto stage = [&](int k0_, int bf) {
#pragma unroll
    for (int j = 0; j < 2; j++) {
      async_ld16(Ag + (size_t)j * 16 * K + k0_, &As[bf][wave * 1024 + j * 512]);
      async_ld16(Bg + (size_t)j * 16 * K + k0_, &Bs[bf][wave * 1024 + j * 512]);
    }
  };

  f32x4 acc[4][4];
#pragma unroll
  for (int mi = 0; mi < 4; mi++)
#pragma unroll
    for (int ni = 0; ni < 4; ni++) acc[mi][ni] = (f32x4){0.f, 0.f, 0.f, 0.f};

  stage(0, 0);
  stage(32, 1);
  int cur = 0;
  for (int k0 = 0; k0 < K; k0 += 32) {
    if (k0 + 64 < K) {
      stage(k0 + 64, cur == 0 ? 2 : cur - 1);   // buf (cur+2)%3
      asm volatile("s_waitcnt vmcnt(8)" ::: "memory");  // tile k0 landed; k+1,k+2 in flight
    } else if (k0 + 32 < K) {
      asm volatile("s_waitcnt vmcnt(4)" ::: "memory");  // k0 landed; k+1 in flight
    } else {
      asm volatile("s_waitcnt vmcnt(0)" ::: "memory");
    }
    __builtin_amdgcn_s_barrier();
    asm volatile("" ::: "memory");
    bf16x8 a[4], b[4];
#pragma unroll
    for (int mi = 0; mi < 4; mi++)
      a[mi] = *(const bf16x8*)(&As[cur][(wm + 16 * mi + fr) * 32 + fq * 8]);
#pragma unroll
    for (int ni = 0; ni < 4; ni++)
      b[ni] = *(const bf16x8*)(&Bs[cur][(wn + 16 * ni + fr) * 32 + fq * 8]);
#pragma unroll
    for (int mi = 0; mi < 4; mi++)
#pragma unroll
      for (int ni = 0; ni < 4; ni++)
        acc[mi][ni] = __builtin_amdgcn_mfma_f32_16x16x32_bf16(
            a[mi], b[ni], acc[mi][ni], 0, 0, 0);
    asm volatile("s_waitcnt lgkmcnt(0)" ::: "memory");
    __builtin_amdgcn_s_barrier();        // all waves done reading buf[cur]
    asm volatile("" ::: "memory");
    cur = (cur == 2) ? 0 : cur + 1;
  }
#pragma unroll
  for (int mi = 0; mi < 4; mi++)
#pragma unroll
    for (int ni = 0; ni < 4; ni++)
#pragma unroll
      for (int r = 0; r < 4; r++) {
        int row = m0 + wm + 16 * mi + fq * 4 + r;
        int col = n0 + wn + 16 * ni + fr;
        float v = acc[mi][ni][r];
        if (OUT_BF16)
          ((unsigned short*)C)[(size_t)row * N + col] = f2b(v);
        else
          ((float*)C)[(size_t)row * N + col] = v;
      }
}

// ------------------------------ RoPE (in-place) ----------------------------
// Used for K only (Q rope is fused into attn's prologue).
template <int LOGH, int STRIDE, int SCALE_Q>
__global__ __launch_bounds__(256) void rope_inplace(unsigned short* __restrict__ X) {
  int p = blockIdx.x * 256 + threadIdx.x;
  int d = p & 63;
  int h = (p >> 6) & ((1 << LOGH) - 1);
  int row = p >> (6 + LOGH);
  int tpos = row & (T_SZ - 1);
  size_t base = (size_t)row * STRIDE + h * 128 + d;
  float u1 = b2f(X[base]), u2 = b2f(X[base + 64]);
  float inv = expf(-(float)d * 0.21586735246819178f);  // theta^(-d/64)
  float ang = (float)tpos * inv;
  float c = cosf(ang), s = sinf(ang);
  float o1 = u1 * c - u2 * s;
  float o2 = u2 * c + u1 * s;
  if (SCALE_Q) { o1 *= 0.08838834764831845f; o2 *= 0.08838834764831845f; }
  X[base]      = f2b(o1);
  X[base + 64] = f2b(o2);
}

// --------- V transpose: QKVb[., 2560 + kvh*128 + n] -> VT[b,kvh,n,t] -------
__global__ __launch_bounds__(256) void transpose_v(
    const unsigned short* __restrict__ V /* QKVb + 2560, row stride 3072 */,
    unsigned short* __restrict__ VT) {
  __shared__ unsigned short tile[64][72];
  int t0 = blockIdx.x * 64;
  int n0 = blockIdx.y * 64;        // within 128
  int bk = blockIdx.z;             // b*4 + kvh
  int b = bk >> 2, kvh = bk & 3;
  int t = threadIdx.x;
#pragma unroll
  for (int i = 0; i < 2; i++) {
    int c = t + 256 * i;           // 512 chunks: 64 t-rows x 8 n-chunks(8)
    int r = c >> 3, cc = c & 7;
    *(uint4*)&tile[r][cc * 8] = *(const uint4*)(
        V + (size_t)(b * T_SZ + t0 + r) * 3072 + kvh * 128 + n0 + cc * 8);
  }
  __syncthreads();
#pragma unroll
  for (int i = 0; i < 2; i++) {
    int c = t + 256 * i;           // 512 chunks: 64 n-rows x 8 t-chunks(8)
    int n = c >> 3, tc = c & 7;
    Pack8 p;
#pragma unroll
    for (int j = 0; j < 8; j++) p.us[j] = tile[tc * 8 + j][n];
    *(uint4*)(VT + ((size_t)bk * 128 + n0 + n) * T_SZ + t0 + tc * 8) = p.v;
  }
}

// -------------------------- flash attention --------------------------------
// S^T variant: compute S^T = K Q^T (A=K, B=Q); PV computes O^T via
// mfma(vf, pf) so all softmax state + O rows live on q-row = fr (lane-local).
//
// Round-11 attn = EXACT R8 (78.8 us best measured).  R9/R10's reg-staged-K
// experiment regressed (101 us): the dead-window vmcnt(0)+ds_write+lgkm chain
// is wave-visible serial work between barriers, while K-DMA staging is fully
// async; measured occupancy didn't rise despite 3 blocks/CU resident.
//  - QBLK=128: 8 waves; K double-buffered DMA, V single-buffered DMA
//    restaged post-PV-barrier; counted vmcnt(2).
//  - log2-domain softmax (Q prescale carries log2e) + defer-max THR=8.
//  - Ps separate buffer, stride 76; LDS 67 KB -> 2 blocks/CU.
__global__ __launch_bounds__(512) void attn(
    const unsigned short* __restrict__ Q,   // QKVb: [BT, 3072], Q in cols 0..2047
    const unsigned short* __restrict__ KV,  // QKVb + 2048: K cols, row stride 3072
    const unsigned short* __restrict__ VT,  // [B,4,128,T]
    unsigned short* __restrict__ O) {       // [BT, 2048]
  __shared__ unsigned short Ks[2][64 * 128];  // [kv][hd], slot-swizzled
  __shared__ unsigned short Vt[128 * 64];     // [hd][kv], slot-swizzled, single
  __shared__ unsigned short Ps[8][16 * 76];   // per-wave P: [q][kv], stride 76
  int qt = blockIdx.z ? blockIdx.x : 15 - blockIdx.x;
  int h = blockIdx.y, b = blockIdx.z;
  int kvh = h >> 2;
  int t = threadIdx.x, lane = t & 63, w = t >> 6;
  int fr = lane & 15, fq = lane >> 4;
  int rsw = fr & 7;                          // read-side swizzle: row&7 == fr&7

  // Q fragments direct from global (read exactly once per block)
  bf16x8 qf[4];
#pragma unroll
  for (int kk = 0; kk < 4; kk++)
    qf[kk] = *(const bf16x8*)(
        Q + (size_t)(b * T_SZ + qt * 128 + w * 16 + fr) * 3072 +
        h * 128 + kk * 32 + fq * 8);

  const unsigned short* Kg = KV + (size_t)b * T_SZ * 3072 + kvh * 128;
  const unsigned short* Vg = VT + (size_t)(b * 4 + kvh) * 128 * T_SZ;

  // staging: 8 waves share each tile.  K: 2 calls/wave x 4 rows(256B);
  // V: 2 calls/wave x 8 rows(128B).  LDS dest linear; source pre-swizzled.
  int k_lr = lane >> 4, k_ls = lane & 15;
  int v_lr = lane >> 3, v_ls = lane & 7;

  auto stage_k = [&](int kt_, int bf) {
#pragma unroll
    for (int j = 0; j < 2; j++) {
      int row = w * 8 + j * 4 + k_lr;       // 0..63
      async_ld16(Kg + (size_t)(kt_ * 64 + row) * 3072 + ((k_ls ^ (row & 7)) << 3),
                 &Ks[bf][(w * 8 + j * 4) * 128]);
    }
  };
  auto stage_v = [&](int kt_) {
#pragma unroll
    for (int j = 0; j < 2; j++) {
      int row = w * 16 + j * 8 + v_lr;      // 0..127 (hd)
      async_ld16(Vg + (size_t)row * T_SZ + kt_ * 64 + ((v_ls ^ (row & 7)) << 3),
                 &Vt[(w * 16 + j * 8) * 64]);
    }
  };

  stage_k(0, 0);     // issued after qf loads: compiler's qf wait leaves DMA in flight
  stage_v(0);

  // fused RoPE + scale on Q: scale = 1/sqrt(128) * log2(e)  (log2-domain
  // softmax).  d = kk*32 + fq*8 + j pairs with d+64 (held in qf[kk+2][j]).
  {
    const float QSCL = 0.08838834764831845f * 1.4426950408889634f;
    float tposf = (float)(qt * 128 + w * 16 + fr);
#pragma unroll
    for (int kk = 0; kk < 2; kk++)
#pragma unroll
      for (int j = 0; j < 8; j++) {
        int d = kk * 32 + (fq << 3) + j;
        float u1 = b2f((unsigned short)qf[kk][j]);
        float u2 = b2f((unsigned short)qf[kk + 2][j]);
        float inv = __expf(-(float)d * 0.21586735246819178f);  // theta^(-d/64)
        float ang = tposf * inv, c, s;
        __sincosf(ang, &s, &c);
        qf[kk][j]     = (short)f2b((u1 * c - u2 * s) * QSCL);
        qf[kk + 2][j] = (short)f2b((u2 * c + u1 * s) * QSCL);
      }
  }

  f32x4 o[8];
#pragma unroll
  for (int i = 0; i < 8; i++) o[i] = (f32x4){0.f, 0.f, 0.f, 0.f};
  float mrow = -1e30f, lrow = 0.f;          // per-lane state; lrow is PARTIAL
  int qg = qt * 128 + w * 16 + fr;          // this lane's global q row
  int nkt = 2 * qt + 2;

  int cur = 0;
  for (int kt = 0; kt < nkt; kt++) {
    if (kt + 1 < nkt) {
      stage_k(kt + 1, cur ^ 1);             // 2 calls in flight across barrier
      asm volatile("s_waitcnt vmcnt(2)" ::: "memory");  // K(kt),V(kt) landed
    } else {
      asm volatile("s_waitcnt vmcnt(0)" ::: "memory");
    }
    __builtin_amdgcn_s_barrier();
    asm volatile("" ::: "memory");

    const unsigned short* KsC = Ks[cur];

    // S^T = K Q^T  (A=K: m=kv, B=Q: n=q).  Lane holds s[nn][r] for
    // q = w*16+fr, kv = kt*64 + nn*16 + fq*4 + r.
    f32x4 s[4];
    __builtin_amdgcn_s_setprio(1);
#pragma unroll
    for (int nn = 0; nn < 4; nn++) {
      s[nn] = (f32x4){0.f, 0.f, 0.f, 0.f};
#pragma unroll
      for (int kk = 0; kk < 4; kk++) {
        bf16x8 kf = *(const bf16x8*)(
            KsC + (nn * 16 + fr) * 128 + ((((kk << 2) + fq) ^ rsw) << 3));
        s[nn] = __builtin_amdgcn_mfma_f32_16x16x32_bf16(kf, qf[kk], s[nn], 0, 0, 0);
      }
    }
    __builtin_amdgcn_s_setprio(0);
    if (kt * 64 + 63 > qg) {                 // tile crosses causal boundary
#pragma unroll
      for (int nn = 0; nn < 4; nn++)
#pragma unroll
        for (int r = 0; r < 4; r++) {
          int kvg = kt * 64 + nn * 16 + fq * 4 + r;
          if (kvg > qg) s[nn][r] = -1e30f;
        }
    }
    // softmax (log2 domain): in-lane max tree, 2-step butterfly across fq
    f32x4 t4;
#pragma unroll
    for (int r = 0; r < 4; r++)
      t4[r] = fmaxf(fmaxf(s[0][r], s[1][r]), fmaxf(s[2][r], s[3][r]));
    float mx = fmaxf(fmaxf(t4[0], t4[1]), fmaxf(t4[2], t4[3]));
    mx = fmaxf(mx, __shfl_xor(mx, 16, 64));
    mx = fmaxf(mx, __shfl_xor(mx, 32, 64));
    // defer-max: only rescale when some row's max grew by >8 (P <= 2^8)
    if (__any(mx > mrow + 8.0f)) {
      float mnew = fmaxf(mrow, mx);
      float alpha = exp2_fast(mrow - mnew);
      lrow *= alpha;
#pragma unroll
      for (int nt = 0; nt < 8; nt++)
#pragma unroll
        for (int r = 0; r < 4; r++) o[nt][r] *= alpha;
      mrow = mnew;
    }
    float sum = 0.f;                         // partial: this lane's 16 values
#pragma unroll
    for (int nn = 0; nn < 4; nn++) {
      ushort4 pk;
      float p0 = exp2_fast(s[nn][0] - mrow); pk.x = f2b(p0);
      float p1 = exp2_fast(s[nn][1] - mrow); pk.y = f2b(p1);
      float p2 = exp2_fast(s[nn][2] - mrow); pk.z = f2b(p2);
      float p3 = exp2_fast(s[nn][3] - mrow); pk.w = f2b(p3);
      sum += (p0 + p1) + (p2 + p3);
      *(ushort4*)(Ps[w] + fr * 76 + nn * 16 + fq * 4) = pk;
    }
    lrow += sum;   // alpha already applied above when rescaled
    // O^T += V^T P^T  (A=vf: m=hd, B=pf: n=q).  o[nt][r] =
    // O[q=fr][hd = nt*16 + fq*4 + r] — same q-row as softmax state.
    __builtin_amdgcn_s_setprio(1);
#pragma unroll
    for (int kk = 0; kk < 2; kk++) {
      bf16x8 pf = *(const bf16x8*)(Ps[w] + fr * 76 + kk * 32 + fq * 8);
#pragma unroll
      for (int nt = 0; nt < 8; nt++) {
        bf16x8 vf = *(const bf16x8*)(
            Vt + (nt * 16 + fr) * 64 + ((((kk << 2) + fq) ^ rsw) << 3));
        o[nt] = __builtin_amdgcn_mfma_f32_16x16x32_bf16(vf, pf, o[nt], 0, 0, 0);
      }
    }
    __builtin_amdgcn_s_setprio(0);
    asm volatile("s_waitcnt lgkmcnt(0)" ::: "memory");
    __builtin_amdgcn_s_barrier();            // all waves done reading Ks[cur], Vt
    asm volatile("" ::: "memory");
    if (kt + 1 < nkt) stage_v(kt + 1);       // overwrite Vt; lands by next vmcnt(2)
    cur ^= 1;
  }
  // epilogue: reduce partial l across the 4 fq-lanes of this q-row, then
  // vectorized stores: lane covers cols nt*16 + fq*4 + 0..3 of row q=fr.
  float lsum = lrow;
  lsum += __shfl_xor(lsum, 16, 64);
  lsum += __shfl_xor(lsum, 32, 64);
  float linv = 1.f / lsum;
  int rowg = b * T_SZ + qt * 128 + w * 16 + fr;
#pragma unroll
  for (int nt = 0; nt < 8; nt++) {
    ushort4 ov;
    ov.x = f2b(o[nt][0] * linv);
    ov.y = f2b(o[nt][1] * linv);
    ov.z = f2b(o[nt][2] * linv);
    ov.w = f2b(o[nt][3] * linv);
    *(ushort4*)(O + (size_t)rowg * 2048 + h * 128 + nt * 16 + fq * 4) = ov;
  }
}

// ---------------------------------------------------------------------------
extern "C" void kernel_launch(void* const* d_in, const int* in_sizes, int n_in,
                              void* d_out, int out_size, void* d_ws, size_t ws_size,
                              hipStream_t stream) {
  const float* x  = (const float*)d_in[0];
  const float* wq = (const float*)d_in[1];
  const float* wk = (const float*)d_in[2];
  const float* wv = (const float*)d_in[3];
  const float* wo = (const float*)d_in[4];
  float* out = (float*)d_out;

  unsigned short* xb   = (unsigned short*)d_ws;             // [4096,2048]
  unsigned short* wqT  = xb   + (size_t)4096 * 2048;        // [3072,2048]: wq|wk|wv transposed
  unsigned short* woT  = wqT  + (size_t)3072 * 2048;        // [2048,2048]
  unsigned short* QKVb = woT  + (size_t)2048 * 2048;        // [4096,3072]: Q | K | V
  unsigned short* VTb  = QKVb + (size_t)4096 * 3072;        // [2,4,128,2048]
  unsigned short* AOb  = VTb  + (size_t)4096 * 512;         // [4096,2048]

  cast_f32_bf16<<<8192, 256, 0, stream>>>(x, xb);
  cast_transpose_all<<<dim3(80, 32), 256, 0, stream>>>(wq, wk, wv, wo, wqT, woT);

  // merged QKV projection: [4096,2048] @ [3072,2048]^T -> [4096,3072]
  gemm_bt<1><<<dim3(24, 32), 256, 0, stream>>>(xb, wqT, QKVb, 4096, 3072, 2048);

  rope_inplace<2, 3072, 0><<<4096, 256, 0, stream>>>(QKVb + 2048); // K only
  transpose_v<<<dim3(32, 2, 8), 256, 0, stream>>>(QKVb + 2560, VTb);

  attn<<<dim3(16, 16, 2), 512, 0, stream>>>(QKVb, QKVb + 2048, VTb, AOb);

  gemm_bt<0><<<dim3(16, 32), 256, 0, stream>>>(AOb, woT, (void*)out, 4096, 2048, 2048);
}

// Round 12
// 295.001 us; speedup vs baseline: 1.4541x; 1.0278x over previous
//
#include <hip/hip_runtime.h>

// ---------------------------------------------------------------------------
// EagerAttention: x[B,T,D] -> QKV proj -> RoPE -> causal GQA attention -> out proj
// B=2 T=2048 D=2048 NH=16 NKV=4 HD=128, fp32 in/out, bf16 MFMA internally.
// Pipeline (5 dispatches): prep -> QKV-GEMM -> prep2 -> attn -> AO-GEMM
// ---------------------------------------------------------------------------

#define T_SZ 2048
#define D_SZ 2048
#define BT   4096   // B*T

typedef __attribute__((ext_vector_type(8))) short bf16x8;
typedef __attribute__((ext_vector_type(4))) float f32x4;

__device__ __forceinline__ unsigned short f2b(float f) {
  unsigned u = __float_as_uint(f);
  u = (u + 0x7fffu + ((u >> 16) & 1u)) >> 16;   // RNE
  return (unsigned short)u;
}
__device__ __forceinline__ float b2f(unsigned short h) {
  return __uint_as_float(((unsigned)h) << 16);
}

#if __has_builtin(__builtin_amdgcn_exp2f)
__device__ __forceinline__ float exp2_fast(float x) { return __builtin_amdgcn_exp2f(x); }
#else
__device__ __forceinline__ float exp2_fast(float x) {
  float r; asm("v_exp_f32 %0, %1" : "=v"(r) : "v"(x)); return r;
}
#endif

// async global->LDS 16B/lane: dest is wave-uniform base + lane*16
__device__ __forceinline__ void async_ld16(const void* g, void* l) {
  __builtin_amdgcn_global_load_lds(
      (const __attribute__((address_space(1))) void*)g,
      (__attribute__((address_space(3))) void*)l, 16, 0, 0);
}

union Pack8 { unsigned short us[8]; uint4 v; };

// ------------- prep: x cast (blocks 0..8191) + weight transpose ------------
// cast: x[4096,2048] f32 -> bf16 (4 elems/thread).
// transpose: W[K=2048,N] f32 -> WT[N,2048] bf16; 2560 blocks partitioned
//   0..31 wq | 32..39 wk | 40..47 wv | 48..79 wo  (x 32 k-tiles)
__global__ __launch_bounds__(256) void prep(
    const float* __restrict__ x, unsigned short* __restrict__ xb,
    const float* __restrict__ wq, const float* __restrict__ wk,
    const float* __restrict__ wv, const float* __restrict__ wo,
    unsigned short* __restrict__ qkvT, unsigned short* __restrict__ woT) {
  __shared__ float tile[64][68];
  int bid = blockIdx.x, t = threadIdx.x;
  if (bid < 8192) {                       // ---- cast part
    int i = (bid * 256 + t) * 4;
    float4 v = *(const float4*)(x + i);
    ushort4 o;
    o.x = f2b(v.x); o.y = f2b(v.y); o.z = f2b(v.z); o.w = f2b(v.w);
    *(ushort4*)(xb + i) = o;
    return;
  }
  int rem = bid - 8192;                   // ---- transpose part (2560 blocks)
  int bx = rem % 80, ky = rem / 80;
  const float* W; unsigned short* WT; int N, nb;
  if (bx < 32)      { W = wq; WT = qkvT;                       N = 2048; nb = bx; }
  else if (bx < 40) { W = wk; WT = qkvT + (size_t)2048 * 2048; N = 512;  nb = bx - 32; }
  else if (bx < 48) { W = wv; WT = qkvT + (size_t)2560 * 2048; N = 512;  nb = bx - 40; }
  else              { W = wo; WT = woT;                        N = 2048; nb = bx - 48; }
  const int K = 2048;
  int n0 = nb * 64, k0 = ky * 64;
#pragma unroll
  for (int i = 0; i < 4; i++) {
    int c = t + 256 * i;              // 1024 chunks: 64 rows x 16 col-chunks(4)
    int r = c >> 4, cc = c & 15;
    float4 v = *(const float4*)(W + (size_t)(k0 + r) * N + n0 + cc * 4);
    tile[r][cc * 4 + 0] = v.x; tile[r][cc * 4 + 1] = v.y;
    tile[r][cc * 4 + 2] = v.z; tile[r][cc * 4 + 3] = v.w;
  }
  __syncthreads();
#pragma unroll
  for (int i = 0; i < 2; i++) {
    int c = t + 256 * i;              // 512 chunks: 64 n x 8 k-chunks(8)
    int n = c >> 3, kc = c & 7;
    Pack8 p;
#pragma unroll
    for (int j = 0; j < 8; j++) p.us[j] = f2b(tile[kc * 8 + j][n]);
    *(uint4*)(WT + (size_t)(n0 + n) * K + k0 + kc * 8) = p.v;
  }
}

// ------------------- GEMM: C[M,N] = A[M,K] @ Bt[N,K]^T ---------------------
// m97 tile (128x128, BK=32, 4 waves, 4x4 16x16 MFMA) + R8's 2-deep pipeline
// (double-buffered LDS, counted vmcnt(4), raw s_barrier) + T1 XCD-aware
// block swizzle: consecutive tiles of a row share the B-panel; clustering a
// contiguous grid chunk per XCD turns those panel re-reads into L2 hits.
// Requires nwg % 8 == 0 (768 and 512 both satisfy).
template <int OUT_BF16>
__global__ __launch_bounds__(256) void gemm_bt(
    const unsigned short* __restrict__ A, const unsigned short* __restrict__ Bt,
    void* __restrict__ C, int M, int N, int K) {
  __shared__ unsigned short As[2][128 * 32];   // lds-DMA layout, unpadded
  __shared__ unsigned short Bs[2][128 * 32];
  int t = threadIdx.x;
  int lane = t & 63, wave = t >> 6;
  // T1 swizzle on the linear block id
  int lin = blockIdx.y * gridDim.x + blockIdx.x;
  int cpx = (gridDim.x * gridDim.y) >> 3;
  int swz = (lin & 7) * cpx + (lin >> 3);
  int bx = swz % gridDim.x, by = swz / gridDim.x;
  int m0 = by * 128, n0 = bx * 128;
  int wm = (wave >> 1) * 64, wn = (wave & 1) * 64;
  int fr = lane & 15, fq = lane >> 4;

  // staging map: wave w stages rows [w*32, w*32+32) of As and Bs (4 calls).
  int srow = wave * 32 + (lane >> 2);
  int scol = (lane & 3) * 8;
  const unsigned short* Ag = A + (size_t)(m0 + srow) * K + scol;
  const unsigned short* Bg = Bt + (size_t)(n0 + srow) * K + scol;

  auto stage = [&](int k0_, int bf) {
#pragma unroll
    for (int j = 0; j < 2; j++) {
      async_ld16(Ag + (size_t)j * 16 * K + k0_, &As[bf][wave * 1024 + j * 512]);
      async_ld16(Bg + (size_t)j * 16 * K + k0_, &Bs[bf][wave * 1024 + j * 512]);
    }
  };

  f32x4 acc[4][4];
#pragma unroll
  for (int mi = 0; mi < 4; mi++)
#pragma unroll
    for (int ni = 0; ni < 4; ni++) acc[mi][ni] = (f32x4){0.f, 0.f, 0.f, 0.f};

  stage(0, 0);
  int cur = 0;
  for (int k0 = 0; k0 < K; k0 += 32) {
    if (k0 + 32 < K) {
      stage(k0 + 32, cur ^ 1);           // 4 calls in flight across barrier
      asm volatile("s_waitcnt vmcnt(4)" ::: "memory");   // tile k0 landed
    } else {
      asm volatile("s_waitcnt vmcnt(0)" ::: "memory");
    }
    __builtin_amdgcn_s_barrier();
    asm volatile("" ::: "memory");
    bf16x8 a[4], b[4];
#pragma unroll
    for (int mi = 0; mi < 4; mi++)
      a[mi] = *(const bf16x8*)(&As[cur][(wm + 16 * mi + fr) * 32 + fq * 8]);
#pragma unroll
    for (int ni = 0; ni < 4; ni++)
      b[ni] = *(const bf16x8*)(&Bs[cur][(wn + 16 * ni + fr) * 32 + fq * 8]);
#pragma unroll
    for (int mi = 0; mi < 4; mi++)
#pragma unroll
      for (int ni = 0; ni < 4; ni++)
        acc[mi][ni] = __builtin_amdgcn_mfma_f32_16x16x32_bf16(
            a[mi], b[ni], acc[mi][ni], 0, 0, 0);
    asm volatile("s_waitcnt lgkmcnt(0)" ::: "memory");
    __builtin_amdgcn_s_barrier();        // all waves done reading buf[cur]
    asm volatile("" ::: "memory");
    cur ^= 1;
  }
#pragma unroll
  for (int mi = 0; mi < 4; mi++)
#pragma unroll
    for (int ni = 0; ni < 4; ni++)
#pragma unroll
      for (int r = 0; r < 4; r++) {
        int row = m0 + wm + 16 * mi + fq * 4 + r;
        int col = n0 + wn + 16 * ni + fr;
        float v = acc[mi][ni][r];
        if (OUT_BF16)
          ((unsigned short*)C)[(size_t)row * N + col] = f2b(v);
        else
          ((float*)C)[(size_t)row * N + col] = v;
      }
}

// ---------- prep2: K rope in-place (blocks 0..4095) + V transpose ----------
__global__ __launch_bounds__(256) void prep2(
    unsigned short* __restrict__ Kx /* QKVb + 2048, row stride 3072 */,
    const unsigned short* __restrict__ V /* QKVb + 2560, row stride 3072 */,
    unsigned short* __restrict__ VT) {
  __shared__ unsigned short tile[64][72];
  int bid = blockIdx.x, t = threadIdx.x;
  if (bid < 4096) {                      // ---- K rope (LOGH=2, STRIDE=3072)
    int p = bid * 256 + t;
    int d = p & 63;
    int h = (p >> 6) & 3;
    int row = p >> 8;
    int tpos = row & (T_SZ - 1);
    size_t base = (size_t)row * 3072 + h * 128 + d;
    float u1 = b2f(Kx[base]), u2 = b2f(Kx[base + 64]);
    float inv = expf(-(float)d * 0.21586735246819178f);  // theta^(-d/64)
    float ang = (float)tpos * inv;
    float c = cosf(ang), s = sinf(ang);
    Kx[base]      = f2b(u1 * c - u2 * s);
    Kx[base + 64] = f2b(u2 * c + u1 * s);
    return;
  }
  int c0 = bid - 4096;                   // ---- V transpose (512 blocks)
  int t0 = (c0 & 31) * 64;
  int n0 = ((c0 >> 5) & 1) * 64;         // within 128
  int bk = c0 >> 6;                      // b*4 + kvh
  int b = bk >> 2, kvh = bk & 3;
#pragma unroll
  for (int i = 0; i < 2; i++) {
    int c = t + 256 * i;                 // 512 chunks: 64 t-rows x 8 n-chunks(8)
    int r = c >> 3, cc = c & 7;
    *(uint4*)&tile[r][cc * 8] = *(const uint4*)(
        V + (size_t)(b * T_SZ + t0 + r) * 3072 + kvh * 128 + n0 + cc * 8);
  }
  __syncthreads();
#pragma unroll
  for (int i = 0; i < 2; i++) {
    int c = t + 256 * i;                 // 512 chunks: 64 n-rows x 8 t-chunks(8)
    int n = c >> 3, tc = c & 7;
    Pack8 p;
#pragma unroll
    for (int j = 0; j < 8; j++) p.us[j] = tile[tc * 8 + j][n];
    *(uint4*)(VT + ((size_t)bk * 128 + n0 + n) * T_SZ + t0 + tc * 8) = p.v;
  }
}

// -------------------------- flash attention --------------------------------
// S^T variant: compute S^T = K Q^T (A=K, B=Q); PV computes O^T via
// mfma(vf, pf) so all softmax state + O rows live on q-row = fr (lane-local).
// EXACT R8 structure (78.8 us best measured):
//  - QBLK=128: 8 waves; K double-buffered DMA, V single-buffered DMA
//    restaged post-PV-barrier; counted vmcnt(2).
//  - fused Q RoPE (+1/sqrt(128)*log2e) in prologue; log2-domain softmax;
//    defer-max THR=8; Ps stride 76; LDS 67 KB -> 2 blocks/CU.
__global__ __launch_bounds__(512) void attn(
    const unsigned short* __restrict__ Q,   // QKVb: [BT, 3072], Q in cols 0..2047
    const unsigned short* __restrict__ KV,  // QKVb + 2048: K cols, row stride 3072
    const unsigned short* __restrict__ VT,  // [B,4,128,T]
    unsigned short* __restrict__ O) {       // [BT, 2048]
  __shared__ unsigned short Ks[2][64 * 128];  // [kv][hd], slot-swizzled
  __shared__ unsigned short Vt[128 * 64];     // [hd][kv], slot-swizzled, single
  __shared__ unsigned short Ps[8][16 * 76];   // per-wave P: [q][kv], stride 76
  int qt = blockIdx.z ? blockIdx.x : 15 - blockIdx.x;
  int h = blockIdx.y, b = blockIdx.z;
  int kvh = h >> 2;
  int t = threadIdx.x, lane = t & 63, w = t >> 6;
  int fr = lane & 15, fq = lane >> 4;
  int rsw = fr & 7;                          // read-side swizzle: row&7 == fr&7

  // Q fragments direct from global (read exactly once per block)
  bf16x8 qf[4];
#pragma unroll
  for (int kk = 0; kk < 4; kk++)
    qf[kk] = *(const bf16x8*)(
        Q + (size_t)(b * T_SZ + qt * 128 + w * 16 + fr) * 3072 +
        h * 128 + kk * 32 + fq * 8);

  const unsigned short* Kg = KV + (size_t)b * T_SZ * 3072 + kvh * 128;
  const unsigned short* Vg = VT + (size_t)(b * 4 + kvh) * 128 * T_SZ;

  // staging: 8 waves share each tile.  K: 2 calls/wave x 4 rows(256B);
  // V: 2 calls/wave x 8 rows(128B).  LDS dest linear; source pre-swizzled.
  int k_lr = lane >> 4, k_ls = lane & 15;
  int v_lr = lane >> 3, v_ls = lane & 7;

  auto stage_k = [&](int kt_, int bf) {
#pragma unroll
    for (int j = 0; j < 2; j++) {
      int row = w * 8 + j * 4 + k_lr;       // 0..63
      async_ld16(Kg + (size_t)(kt_ * 64 + row) * 3072 + ((k_ls ^ (row & 7)) << 3),
                 &Ks[bf][(w * 8 + j * 4) * 128]);
    }
  };
  auto stage_v = [&](int kt_) {
#pragma unroll
    for (int j = 0; j < 2; j++) {
      int row = w * 16 + j * 8 + v_lr;      // 0..127 (hd)
      async_ld16(Vg + (size_t)row * T_SZ + kt_ * 64 + ((v_ls ^ (row & 7)) << 3),
                 &Vt[(w * 16 + j * 8) * 64]);
    }
  };

  stage_k(0, 0);     // issued after qf loads: compiler's qf wait leaves DMA in flight
  stage_v(0);

  // fused RoPE + scale on Q: scale = 1/sqrt(128) * log2(e)  (log2-domain
  // softmax).  d = kk*32 + fq*8 + j pairs with d+64 (held in qf[kk+2][j]).
  {
    const float QSCL = 0.08838834764831845f * 1.4426950408889634f;
    float tposf = (float)(qt * 128 + w * 16 + fr);
#pragma unroll
    for (int kk = 0; kk < 2; kk++)
#pragma unroll
      for (int j = 0; j < 8; j++) {
        int d = kk * 32 + (fq << 3) + j;
        float u1 = b2f((unsigned short)qf[kk][j]);
        float u2 = b2f((unsigned short)qf[kk + 2][j]);
        float inv = __expf(-(float)d * 0.21586735246819178f);  // theta^(-d/64)
        float ang = tposf * inv, c, s;
        __sincosf(ang, &s, &c);
        qf[kk][j]     = (short)f2b((u1 * c - u2 * s) * QSCL);
        qf[kk + 2][j] = (short)f2b((u2 * c + u1 * s) * QSCL);
      }
  }

  f32x4 o[8];
#pragma unroll
  for (int i = 0; i < 8; i++) o[i] = (f32x4){0.f, 0.f, 0.f, 0.f};
  float mrow = -1e30f, lrow = 0.f;          // per-lane state; lrow is PARTIAL
  int qg = qt * 128 + w * 16 + fr;          // this lane's global q row
  int nkt = 2 * qt + 2;

  int cur = 0;
  for (int kt = 0; kt < nkt; kt++) {
    if (kt + 1 < nkt) {
      stage_k(kt + 1, cur ^ 1);             // 2 calls in flight across barrier
      asm volatile("s_waitcnt vmcnt(2)" ::: "memory");  // K(kt),V(kt) landed
    } else {
      asm volatile("s_waitcnt vmcnt(0)" ::: "memory");
    }
    __builtin_amdgcn_s_barrier();
    asm volatile("" ::: "memory");

    const unsigned short* KsC = Ks[cur];

    // S^T = K Q^T  (A=K: m=kv, B=Q: n=q).  Lane holds s[nn][r] for
    // q = w*16+fr, kv = kt*64 + nn*16 + fq*4 + r.
    f32x4 s[4];
    __builtin_amdgcn_s_setprio(1);
#pragma unroll
    for (int nn = 0; nn < 4; nn++) {
      s[nn] = (f32x4){0.f, 0.f, 0.f, 0.f};
#pragma unroll
      for (int kk = 0; kk < 4; kk++) {
        bf16x8 kf = *(const bf16x8*)(
            KsC + (nn * 16 + fr) * 128 + ((((kk << 2) + fq) ^ rsw) << 3));
        s[nn] = __builtin_amdgcn_mfma_f32_16x16x32_bf16(kf, qf[kk], s[nn], 0, 0, 0);
      }
    }
    __builtin_amdgcn_s_setprio(0);
    if (kt * 64 + 63 > qg) {                 // tile crosses causal boundary
#pragma unroll
      for (int nn = 0; nn < 4; nn++)
#pragma unroll
        for (int r = 0; r < 4; r++) {
          int kvg = kt * 64 + nn * 16 + fq * 4 + r;
          if (kvg > qg) s[nn][r] = -1e30f;
        }
    }
    // softmax (log2 domain): in-lane max tree, 2-step butterfly across fq
    f32x4 t4;
#pragma unroll
    for (int r = 0; r < 4; r++)
      t4[r] = fmaxf(fmaxf(s[0][r], s[1][r]), fmaxf(s[2][r], s[3][r]));
    float mx = fmaxf(fmaxf(t4[0], t4[1]), fmaxf(t4[2], t4[3]));
    mx = fmaxf(mx, __shfl_xor(mx, 16, 64));
    mx = fmaxf(mx, __shfl_xor(mx, 32, 64));
    // defer-max: only rescale when some row's max grew by >8 (P <= 2^8)
    if (__any(mx > mrow + 8.0f)) {
      float mnew = fmaxf(mrow, mx);
      float alpha = exp2_fast(mrow - mnew);
      lrow *= alpha;
#pragma unroll
      for (int nt = 0; nt < 8; nt++)
#pragma unroll
        for (int r = 0; r < 4; r++) o[nt][r] *= alpha;
      mrow = mnew;
    }
    float sum = 0.f;                         // partial: this lane's 16 values
#pragma unroll
    for (int nn = 0; nn < 4; nn++) {
      ushort4 pk;
      float p0 = exp2_fast(s[nn][0] - mrow); pk.x = f2b(p0);
      float p1 = exp2_fast(s[nn][1] - mrow); pk.y = f2b(p1);
      float p2 = exp2_fast(s[nn][2] - mrow); pk.z = f2b(p2);
      float p3 = exp2_fast(s[nn][3] - mrow); pk.w = f2b(p3);
      sum += (p0 + p1) + (p2 + p3);
      *(ushort4*)(Ps[w] + fr * 76 + nn * 16 + fq * 4) = pk;
    }
    lrow += sum;   // alpha already applied above when rescaled
    // O^T += V^T P^T  (A=vf: m=hd, B=pf: n=q).  o[nt][r] =
    // O[q=fr][hd = nt*16 + fq*4 + r] — same q-row as softmax state.
    __builtin_amdgcn_s_setprio(1);
#pragma unroll
    for (int kk = 0; kk < 2; kk++) {
      bf16x8 pf = *(const bf16x8*)(Ps[w] + fr * 76 + kk * 32 + fq * 8);
#pragma unroll
      for (int nt = 0; nt < 8; nt++) {
        bf16x8 vf = *(const bf16x8*)(
            Vt + (nt * 16 + fr) * 64 + ((((kk << 2) + fq) ^ rsw) << 3));
        o[nt] = __builtin_amdgcn_mfma_f32_16x16x32_bf16(vf, pf, o[nt], 0, 0, 0);
      }
    }
    __builtin_amdgcn_s_setprio(0);
    asm volatile("s_waitcnt lgkmcnt(0)" ::: "memory");
    __builtin_amdgcn_s_barrier();            // all waves done reading Ks[cur], Vt
    asm volatile("" ::: "memory");
    if (kt + 1 < nkt) stage_v(kt + 1);       // overwrite Vt; lands by next vmcnt(2)
    cur ^= 1;
  }
  // epilogue: reduce partial l across the 4 fq-lanes of this q-row, then
  // vectorized stores: lane covers cols nt*16 + fq*4 + 0..3 of row q=fr.
  float lsum = lrow;
  lsum += __shfl_xor(lsum, 16, 64);
  lsum += __shfl_xor(lsum, 32, 64);
  float linv = 1.f / lsum;
  int rowg = b * T_SZ + qt * 128 + w * 16 + fr;
#pragma unroll
  for (int nt = 0; nt < 8; nt++) {
    ushort4 ov;
    ov.x = f2b(o[nt][0] * linv);
    ov.y = f2b(o[nt][1] * linv);
    ov.z = f2b(o[nt][2] * linv);
    ov.w = f2b(o[nt][3] * linv);
    *(ushort4*)(O + (size_t)rowg * 2048 + h * 128 + nt * 16 + fq * 4) = ov;
  }
}

// ---------------------------------------------------------------------------
extern "C" void kernel_launch(void* const* d_in, const int* in_sizes, int n_in,
                              void* d_out, int out_size, void* d_ws, size_t ws_size,
                              hipStream_t stream) {
  const float* x  = (const float*)d_in[0];
  const float* wq = (const float*)d_in[1];
  const float* wk = (const float*)d_in[2];
  const float* wv = (const float*)d_in[3];
  const float* wo = (const float*)d_in[4];
  float* out = (float*)d_out;

  unsigned short* xb   = (unsigned short*)d_ws;             // [4096,2048]
  unsigned short* wqT  = xb   + (size_t)4096 * 2048;        // [3072,2048]: wq|wk|wv transposed
  unsigned short* woT  = wqT  + (size_t)3072 * 2048;        // [2048,2048]
  unsigned short* QKVb = woT  + (size_t)2048 * 2048;        // [4096,3072]: Q | K | V
  unsigned short* VTb  = QKVb + (size_t)4096 * 3072;        // [2,4,128,2048]
  unsigned short* AOb  = VTb  + (size_t)4096 * 512;         // [4096,2048]

  // prep: x cast (8192 blocks) + all weight transposes (2560 blocks)
  prep<<<10752, 256, 0, stream>>>(x, xb, wq, wk, wv, wo, wqT, woT);

  // merged QKV projection: [4096,2048] @ [3072,2048]^T -> [4096,3072]
  gemm_bt<1><<<dim3(24, 32), 256, 0, stream>>>(xb, wqT, QKVb, 4096, 3072, 2048);

  // prep2: K rope (4096 blocks) + V transpose (512 blocks)
  prep2<<<4608, 256, 0, stream>>>(QKVb + 2048, QKVb + 2560, VTb);

  attn<<<dim3(16, 16, 2), 512, 0, stream>>>(QKVb, QKVb + 2048, VTb, AOb);

  gemm_bt<0><<<dim3(16, 32), 256, 0, stream>>>(AOb, woT, (void*)out, 4096, 2048, 2048);
}

// Round 13
// 288.503 us; speedup vs baseline: 1.4869x; 1.0225x over previous
//
#include <hip/hip_runtime.h>

// ---------------------------------------------------------------------------
// EagerAttention: x[B,T,D] -> QKV proj -> RoPE -> causal GQA attention -> out proj
// B=2 T=2048 D=2048 NH=16 NKV=4 HD=128, fp32 in/out, bf16 MFMA internally.
// Pipeline (4 dispatches): prep -> QKV-GEMM(fused rope-K + V-transpose) ->
//                          attn -> AO-GEMM
// ---------------------------------------------------------------------------

#define T_SZ 2048
#define D_SZ 2048
#define BT   4096   // B*T

typedef __attribute__((ext_vector_type(8))) short bf16x8;
typedef __attribute__((ext_vector_type(4))) float f32x4;

__device__ __forceinline__ unsigned short f2b(float f) {
  unsigned u = __float_as_uint(f);
  u = (u + 0x7fffu + ((u >> 16) & 1u)) >> 16;   // RNE
  return (unsigned short)u;
}
__device__ __forceinline__ float b2f(unsigned short h) {
  return __uint_as_float(((unsigned)h) << 16);
}

#if __has_builtin(__builtin_amdgcn_exp2f)
__device__ __forceinline__ float exp2_fast(float x) { return __builtin_amdgcn_exp2f(x); }
#else
__device__ __forceinline__ float exp2_fast(float x) {
  float r; asm("v_exp_f32 %0, %1" : "=v"(r) : "v"(x)); return r;
}
#endif

// async global->LDS 16B/lane: dest is wave-uniform base + lane*16
__device__ __forceinline__ void async_ld16(const void* g, void* l) {
  __builtin_amdgcn_global_load_lds(
      (const __attribute__((address_space(1))) void*)g,
      (__attribute__((address_space(3))) void*)l, 16, 0, 0);
}

union Pack8 { unsigned short us[8]; uint4 v; };

// ------------- prep: x cast (blocks 0..8191) + weight transpose ------------
// cast: x[4096,2048] f32 -> bf16 (4 elems/thread).
// transpose: W[K=2048,N] f32 -> WT[N,2048] bf16; 2560 blocks partitioned
//   0..31 wq | 32..39 wk | 40..47 wv | 48..79 wo  (x 32 k-tiles)
__global__ __launch_bounds__(256) void prep(
    const float* __restrict__ x, unsigned short* __restrict__ xb,
    const float* __restrict__ wq, const float* __restrict__ wk,
    const float* __restrict__ wv, const float* __restrict__ wo,
    unsigned short* __restrict__ qkvT, unsigned short* __restrict__ woT) {
  __shared__ float tile[64][68];
  int bid = blockIdx.x, t = threadIdx.x;
  if (bid < 8192) {                       // ---- cast part
    int i = (bid * 256 + t) * 4;
    float4 v = *(const float4*)(x + i);
    ushort4 o;
    o.x = f2b(v.x); o.y = f2b(v.y); o.z = f2b(v.z); o.w = f2b(v.w);
    *(ushort4*)(xb + i) = o;
    return;
  }
  int rem = bid - 8192;                   // ---- transpose part (2560 blocks)
  int bx = rem % 80, ky = rem / 80;
  const float* W; unsigned short* WT; int N, nb;
  if (bx < 32)      { W = wq; WT = qkvT;                       N = 2048; nb = bx; }
  else if (bx < 40) { W = wk; WT = qkvT + (size_t)2048 * 2048; N = 512;  nb = bx - 32; }
  else if (bx < 48) { W = wv; WT = qkvT + (size_t)2560 * 2048; N = 512;  nb = bx - 40; }
  else              { W = wo; WT = woT;                        N = 2048; nb = bx - 48; }
  const int K = 2048;
  int n0 = nb * 64, k0 = ky * 64;
#pragma unroll
  for (int i = 0; i < 4; i++) {
    int c = t + 256 * i;              // 1024 chunks: 64 rows x 16 col-chunks(4)
    int r = c >> 4, cc = c & 15;
    float4 v = *(const float4*)(W + (size_t)(k0 + r) * N + n0 + cc * 4);
    tile[r][cc * 4 + 0] = v.x; tile[r][cc * 4 + 1] = v.y;
    tile[r][cc * 4 + 2] = v.z; tile[r][cc * 4 + 3] = v.w;
  }
  __syncthreads();
#pragma unroll
  for (int i = 0; i < 2; i++) {
    int c = t + 256 * i;              // 512 chunks: 64 n x 8 k-chunks(8)
    int n = c >> 3, kc = c & 7;
    Pack8 p;
#pragma unroll
    for (int j = 0; j < 8; j++) p.us[j] = f2b(tile[kc * 8 + j][n]);
    *(uint4*)(WT + (size_t)(n0 + n) * K + k0 + kc * 8) = p.v;
  }
}

// ------------------- GEMM: C[M,N] = A[M,K] @ Bt[N,K]^T ---------------------
// m97 tile (128x128, BK=32, 4 waves, 4x4 16x16 MFMA) + 2-deep counted-vmcnt
// pipeline + T1 XCD swizzle (nwg % 8 == 0 for both uses).
// MODE 0: plain f32 output (AO GEMM).
// MODE 1: QKV-fused (N=3072): Q cols -> bf16 store; K cols -> RoPE applied
//   via a 128x128 bf16 LDS exchange (reusing the dead As/Bs space) then bf16
//   store; V cols -> transposed through the same exchange straight to
//   VT[b,kvh,hd,t] (QKVb's V region never written).
template <int MODE>
__global__ __launch_bounds__(256) void gemm_bt(
    const unsigned short* __restrict__ A, const unsigned short* __restrict__ Bt,
    void* __restrict__ C, unsigned short* __restrict__ VT,
    int M, int N, int K) {
  __shared__ unsigned short smem[4][128 * 32];   // As = smem[0..1], Bs = smem[2..3]
  int t = threadIdx.x;
  int lane = t & 63, wave = t >> 6;
  // T1 swizzle on the linear block id
  int lin = blockIdx.y * gridDim.x + blockIdx.x;
  int cpx = (gridDim.x * gridDim.y) >> 3;
  int swz = (lin & 7) * cpx + (lin >> 3);
  int bx = swz % gridDim.x, by = swz / gridDim.x;
  int m0 = by * 128, n0 = bx * 128;
  int wm = (wave >> 1) * 64, wn = (wave & 1) * 64;
  int fr = lane & 15, fq = lane >> 4;

  // staging map: wave w stages rows [w*32, w*32+32) of As and Bs (4 calls).
  int srow = wave * 32 + (lane >> 2);
  int scol = (lane & 3) * 8;
  const unsigned short* Ag = A + (size_t)(m0 + srow) * K + scol;
  const unsigned short* Bg = Bt + (size_t)(n0 + srow) * K + scol;

  auto stage = [&](int k0_, int bf) {
#pragma unroll
    for (int j = 0; j < 2; j++) {
      async_ld16(Ag + (size_t)j * 16 * K + k0_, &smem[bf][wave * 1024 + j * 512]);
      async_ld16(Bg + (size_t)j * 16 * K + k0_, &smem[2 + bf][wave * 1024 + j * 512]);
    }
  };

  f32x4 acc[4][4];
#pragma unroll
  for (int mi = 0; mi < 4; mi++)
#pragma unroll
    for (int ni = 0; ni < 4; ni++) acc[mi][ni] = (f32x4){0.f, 0.f, 0.f, 0.f};

  stage(0, 0);
  int cur = 0;
  for (int k0 = 0; k0 < K; k0 += 32) {
    if (k0 + 32 < K) {
      stage(k0 + 32, cur ^ 1);           // 4 calls in flight across barrier
      asm volatile("s_waitcnt vmcnt(4)" ::: "memory");   // tile k0 landed
    } else {
      asm volatile("s_waitcnt vmcnt(0)" ::: "memory");
    }
    __builtin_amdgcn_s_barrier();
    asm volatile("" ::: "memory");
    bf16x8 a[4], b[4];
#pragma unroll
    for (int mi = 0; mi < 4; mi++)
      a[mi] = *(const bf16x8*)(&smem[cur][(wm + 16 * mi + fr) * 32 + fq * 8]);
#pragma unroll
    for (int ni = 0; ni < 4; ni++)
      b[ni] = *(const bf16x8*)(&smem[2 + cur][(wn + 16 * ni + fr) * 32 + fq * 8]);
#pragma unroll
    for (int mi = 0; mi < 4; mi++)
#pragma unroll
      for (int ni = 0; ni < 4; ni++)
        acc[mi][ni] = __builtin_amdgcn_mfma_f32_16x16x32_bf16(
            a[mi], b[ni], acc[mi][ni], 0, 0, 0);
    asm volatile("s_waitcnt lgkmcnt(0)" ::: "memory");
    __builtin_amdgcn_s_barrier();        // all waves done reading buf[cur]
    asm volatile("" ::: "memory");
    cur ^= 1;
  }

  if (MODE == 0) {                       // ---------------- plain f32 output
#pragma unroll
    for (int mi = 0; mi < 4; mi++)
#pragma unroll
      for (int ni = 0; ni < 4; ni++)
#pragma unroll
        for (int r = 0; r < 4; r++) {
          int row = m0 + wm + 16 * mi + fq * 4 + r;
          int col = n0 + wn + 16 * ni + fr;
          ((float*)C)[(size_t)row * N + col] = acc[mi][ni][r];
        }
    return;
  }

  // ---------------- QKV fused epilogue (MODE 1) ----------------
  if (n0 < 2048) {                       // Q region: plain bf16 store
#pragma unroll
    for (int mi = 0; mi < 4; mi++)
#pragma unroll
      for (int ni = 0; ni < 4; ni++)
#pragma unroll
        for (int r = 0; r < 4; r++) {
          int row = m0 + wm + 16 * mi + fq * 4 + r;
          int col = n0 + wn + 16 * ni + fr;
          ((unsigned short*)C)[(size_t)row * N + col] = f2b(acc[mi][ni][r]);
        }
    return;
  }

  // K or V region: round-trip through a 128x128 bf16 exchange tile in the
  // (now dead) As/Bs space.  XOR-swizzled so V's column reads don't conflict.
  unsigned short* Ex = &smem[0][0];      // 16384 shorts = 32 KB, exact fit
#pragma unroll
  for (int mi = 0; mi < 4; mi++)
#pragma unroll
    for (int ni = 0; ni < 4; ni++)
#pragma unroll
      for (int r = 0; r < 4; r++) {
        int row = wm + 16 * mi + fq * 4 + r;
        int col = wn + 16 * ni + fr;
        Ex[row * 128 + (col ^ ((row & 15) << 3))] = f2b(acc[mi][ni][r]);
      }
  __syncthreads();

  if (n0 < 2560) {                       // ---- K region: RoPE then store
    // 8192 (row, d) pairs / 256 threads = 32 per thread; lanes cover
    // consecutive d within one row -> coalesced 128B stores.
    for (int i = 0; i < 32; i++) {
      int flat = t + 256 * i;
      int row = flat >> 6;               // 0..127
      int d = flat & 63;
      int sw = (row & 15) << 3;
      float u1 = b2f(Ex[row * 128 + (d ^ sw)]);
      float u2 = b2f(Ex[row * 128 + ((d + 64) ^ sw)]);
      int tpos = (m0 + row) & (T_SZ - 1);
      float inv = __expf(-(float)d * 0.21586735246819178f);  // theta^(-d/64)
      float ang = (float)tpos * inv, cc, ss;
      __sincosf(ang, &ss, &cc);
      ((unsigned short*)C)[(size_t)(m0 + row) * N + n0 + d]      = f2b(u1 * cc - u2 * ss);
      ((unsigned short*)C)[(size_t)(m0 + row) * N + n0 + d + 64] = f2b(u2 * cc + u1 * ss);
    }
  } else {                               // ---- V region: transpose -> VT
    int kvh = (n0 - 2560) >> 7;
    int bb = m0 >> 11, t0l = m0 & (T_SZ - 1);   // 128-row tile never crosses b
    int bk = bb * 4 + kvh;
    // 128 n-rows x 16 t-chunks(8) = 2048 chunks / 256 threads = 8 each;
    // 16 consecutive lanes share n -> 256B coalesced stores.
    for (int i = 0; i < 8; i++) {
      int chunk = t + 256 * i;
      int n = chunk >> 4;                // 0..127
      int tc = chunk & 15;
      Pack8 p;
#pragma unroll
      for (int j = 0; j < 8; j++) {
        int tt = tc * 8 + j;
        p.us[j] = Ex[tt * 128 + (n ^ ((tt & 15) << 3))];
      }
      *(uint4*)(VT + ((size_t)(bk * 128 + n)) * T_SZ + t0l + tc * 8) = p.v;
    }
  }
}

// -------------------------- flash attention --------------------------------
// S^T variant: compute S^T = K Q^T (A=K, B=Q); PV computes O^T via
// mfma(vf, pf) so all softmax state + O rows live on q-row = fr (lane-local).
// EXACT R8 structure (78 us best measured):
//  - QBLK=128: 8 waves; K double-buffered DMA, V single-buffered DMA
//    restaged post-PV-barrier; counted vmcnt(2).
//  - fused Q RoPE (+1/sqrt(128)*log2e) in prologue; log2-domain softmax;
//    defer-max THR=8; Ps stride 76; LDS 67 KB -> 2 blocks/CU.
__global__ __launch_bounds__(512) void attn(
    const unsigned short* __restrict__ Q,   // QKVb: [BT, 3072], Q in cols 0..2047
    const unsigned short* __restrict__ KV,  // QKVb + 2048: K cols, row stride 3072
    const unsigned short* __restrict__ VT,  // [B,4,128,T]
    unsigned short* __restrict__ O) {       // [BT, 2048]
  __shared__ unsigned short Ks[2][64 * 128];  // [kv][hd], slot-swizzled
  __shared__ unsigned short Vt[128 * 64];     // [hd][kv], slot-swizzled, single
  __shared__ unsigned short Ps[8][16 * 76];   // per-wave P: [q][kv], stride 76
  int qt = blockIdx.z ? blockIdx.x : 15 - blockIdx.x;
  int h = blockIdx.y, b = blockIdx.z;
  int kvh = h >> 2;
  int t = threadIdx.x, lane = t & 63, w = t >> 6;
  int fr = lane & 15, fq = lane >> 4;
  int rsw = fr & 7;                          // read-side swizzle: row&7 == fr&7

  // Q fragments direct from global (read exactly once per block)
  bf16x8 qf[4];
#pragma unroll
  for (int kk = 0; kk < 4; kk++)
    qf[kk] = *(const bf16x8*)(
        Q + (size_t)(b * T_SZ + qt * 128 + w * 16 + fr) * 3072 +
        h * 128 + kk * 32 + fq * 8);

  const unsigned short* Kg = KV + (size_t)b * T_SZ * 3072 + kvh * 128;
  const unsigned short* Vg = VT + (size_t)(b * 4 + kvh) * 128 * T_SZ;

  // staging: 8 waves share each tile.  K: 2 calls/wave x 4 rows(256B);
  // V: 2 calls/wave x 8 rows(128B).  LDS dest linear; source pre-swizzled.
  int k_lr = lane >> 4, k_ls = lane & 15;
  int v_lr = lane >> 3, v_ls = lane & 7;

  auto stage_k = [&](int kt_, int bf) {
#pragma unroll
    for (int j = 0; j < 2; j++) {
      int row = w * 8 + j * 4 + k_lr;       // 0..63
      async_ld16(Kg + (size_t)(kt_ * 64 + row) * 3072 + ((k_ls ^ (row & 7)) << 3),
                 &Ks[bf][(w * 8 + j * 4) * 128]);
    }
  };
  auto stage_v = [&](int kt_) {
#pragma unroll
    for (int j = 0; j < 2; j++) {
      int row = w * 16 + j * 8 + v_lr;      // 0..127 (hd)
      async_ld16(Vg + (size_t)row * T_SZ + kt_ * 64 + ((v_ls ^ (row & 7)) << 3),
                 &Vt[(w * 16 + j * 8) * 64]);
    }
  };

  stage_k(0, 0);     // issued after qf loads: compiler's qf wait leaves DMA in flight
  stage_v(0);

  // fused RoPE + scale on Q: scale = 1/sqrt(128) * log2(e)  (log2-domain
  // softmax).  d = kk*32 + fq*8 + j pairs with d+64 (held in qf[kk+2][j]).
  {
    const float QSCL = 0.08838834764831845f * 1.4426950408889634f;
    float tposf = (float)(qt * 128 + w * 16 + fr);
#pragma unroll
    for (int kk = 0; kk < 2; kk++)
#pragma unroll
      for (int j = 0; j < 8; j++) {
        int d = kk * 32 + (fq << 3) + j;
        float u1 = b2f((unsigned short)qf[kk][j]);
        float u2 = b2f((unsigned short)qf[kk + 2][j]);
        float inv = __expf(-(float)d * 0.21586735246819178f);  // theta^(-d/64)
        float ang = tposf * inv, c, s;
        __sincosf(ang, &s, &c);
        qf[kk][j]     = (short)f2b((u1 * c - u2 * s) * QSCL);
        qf[kk + 2][j] = (short)f2b((u2 * c + u1 * s) * QSCL);
      }
  }

  f32x4 o[8];
#pragma unroll
  for (int i = 0; i < 8; i++) o[i] = (f32x4){0.f, 0.f, 0.f, 0.f};
  float mrow = -1e30f, lrow = 0.f;          // per-lane state; lrow is PARTIAL
  int qg = qt * 128 + w * 16 + fr;          // this lane's global q row
  int nkt = 2 * qt + 2;

  int cur = 0;
  for (int kt = 0; kt < nkt; kt++) {
    if (kt + 1 < nkt) {
      stage_k(kt + 1, cur ^ 1);             // 2 calls in flight across barrier
      asm volatile("s_waitcnt vmcnt(2)" ::: "memory");  // K(kt),V(kt) landed
    } else {
      asm volatile("s_waitcnt vmcnt(0)" ::: "memory");
    }
    __builtin_amdgcn_s_barrier();
    asm volatile("" ::: "memory");

    const unsigned short* KsC = Ks[cur];

    // S^T = K Q^T  (A=K: m=kv, B=Q: n=q).  Lane holds s[nn][r] for
    // q = w*16+fr, kv = kt*64 + nn*16 + fq*4 + r.
    f32x4 s[4];
    __builtin_amdgcn_s_setprio(1);
#pragma unroll
    for (int nn = 0; nn < 4; nn++) {
      s[nn] = (f32x4){0.f, 0.f, 0.f, 0.f};
#pragma unroll
      for (int kk = 0; kk < 4; kk++) {
        bf16x8 kf = *(const bf16x8*)(
            KsC + (nn * 16 + fr) * 128 + ((((kk << 2) + fq) ^ rsw) << 3));
        s[nn] = __builtin_amdgcn_mfma_f32_16x16x32_bf16(kf, qf[kk], s[nn], 0, 0, 0);
      }
    }
    __builtin_amdgcn_s_setprio(0);
    if (kt * 64 + 63 > qg) {                 // tile crosses causal boundary
#pragma unroll
      for (int nn = 0; nn < 4; nn++)
#pragma unroll
        for (int r = 0; r < 4; r++) {
          int kvg = kt * 64 + nn * 16 + fq * 4 + r;
          if (kvg > qg) s[nn][r] = -1e30f;
        }
    }
    // softmax (log2 domain): in-lane max tree, 2-step butterfly across fq
    f32x4 t4;
#pragma unroll
    for (int r = 0; r < 4; r++)
      t4[r] = fmaxf(fmaxf(s[0][r], s[1][r]), fmaxf(s[2][r], s[3][r]));
    float mx = fmaxf(fmaxf(t4[0], t4[1]), fmaxf(t4[2], t4[3]));
    mx = fmaxf(mx, __shfl_xor(mx, 16, 64));
    mx = fmaxf(mx, __shfl_xor(mx, 32, 64));
    // defer-max: only rescale when some row's max grew by >8 (P <= 2^8)
    if (__any(mx > mrow + 8.0f)) {
      float mnew = fmaxf(mrow, mx);
      float alpha = exp2_fast(mrow - mnew);
      lrow *= alpha;
#pragma unroll
      for (int nt = 0; nt < 8; nt++)
#pragma unroll
        for (int r = 0; r < 4; r++) o[nt][r] *= alpha;
      mrow = mnew;
    }
    float sum = 0.f;                         // partial: this lane's 16 values
#pragma unroll
    for (int nn = 0; nn < 4; nn++) {
      ushort4 pk;
      float p0 = exp2_fast(s[nn][0] - mrow); pk.x = f2b(p0);
      float p1 = exp2_fast(s[nn][1] - mrow); pk.y = f2b(p1);
      float p2 = exp2_fast(s[nn][2] - mrow); pk.z = f2b(p2);
      float p3 = exp2_fast(s[nn][3] - mrow); pk.w = f2b(p3);
      sum += (p0 + p1) + (p2 + p3);
      *(ushort4*)(Ps[w] + fr * 76 + nn * 16 + fq * 4) = pk;
    }
    lrow += sum;   // alpha already applied above when rescaled
    // O^T += V^T P^T  (A=vf: m=hd, B=pf: n=q).  o[nt][r] =
    // O[q=fr][hd = nt*16 + fq*4 + r] — same q-row as softmax state.
    __builtin_amdgcn_s_setprio(1);
#pragma unroll
    for (int kk = 0; kk < 2; kk++) {
      bf16x8 pf = *(const bf16x8*)(Ps[w] + fr * 76 + kk * 32 + fq * 8);
#pragma unroll
      for (int nt = 0; nt < 8; nt++) {
        bf16x8 vf = *(const bf16x8*)(
            Vt + (nt * 16 + fr) * 64 + ((((kk << 2) + fq) ^ rsw) << 3));
        o[nt] = __builtin_amdgcn_mfma_f32_16x16x32_bf16(vf, pf, o[nt], 0, 0, 0);
      }
    }
    __builtin_amdgcn_s_setprio(0);
    asm volatile("s_waitcnt lgkmcnt(0)" ::: "memory");
    __builtin_amdgcn_s_barrier();            // all waves done reading Ks[cur], Vt
    asm volatile("" ::: "memory");
    if (kt + 1 < nkt) stage_v(kt + 1);       // overwrite Vt; lands by next vmcnt(2)
    cur ^= 1;
  }
  // epilogue: reduce partial l across the 4 fq-lanes of this q-row, then
  // vectorized stores: lane covers cols nt*16 + fq*4 + 0..3 of row q=fr.
  float lsum = lrow;
  lsum += __shfl_xor(lsum, 16, 64);
  lsum += __shfl_xor(lsum, 32, 64);
  float linv = 1.f / lsum;
  int rowg = b * T_SZ + qt * 128 + w * 16 + fr;
#pragma unroll
  for (int nt = 0; nt < 8; nt++) {
    ushort4 ov;
    ov.x = f2b(o[nt][0] * linv);
    ov.y = f2b(o[nt][1] * linv);
    ov.z = f2b(o[nt][2] * linv);
    ov.w = f2b(o[nt][3] * linv);
    *(ushort4*)(O + (size_t)rowg * 2048 + h * 128 + nt * 16 + fq * 4) = ov;
  }
}

// ---------------------------------------------------------------------------
extern "C" void kernel_launch(void* const* d_in, const int* in_sizes, int n_in,
                              void* d_out, int out_size, void* d_ws, size_t ws_size,
                              hipStream_t stream) {
  const float* x  = (const float*)d_in[0];
  const float* wq = (const float*)d_in[1];
  const float* wk = (const float*)d_in[2];
  const float* wv = (const float*)d_in[3];
  const float* wo = (const float*)d_in[4];
  float* out = (float*)d_out;

  unsigned short* xb   = (unsigned short*)d_ws;             // [4096,2048]
  unsigned short* wqT  = xb   + (size_t)4096 * 2048;        // [3072,2048]: wq|wk|wv transposed
  unsigned short* woT  = wqT  + (size_t)3072 * 2048;        // [2048,2048]
  unsigned short* QKVb = woT  + (size_t)2048 * 2048;        // [4096,3072]: Q | K (V unused)
  unsigned short* VTb  = QKVb + (size_t)4096 * 3072;        // [2,4,128,2048]
  unsigned short* AOb  = VTb  + (size_t)4096 * 512;         // [4096,2048]

  // prep: x cast (8192 blocks) + all weight transposes (2560 blocks)
  prep<<<10752, 256, 0, stream>>>(x, xb, wq, wk, wv, wo, wqT, woT);

  // merged QKV projection + fused K-RoPE + V-transpose:
  // [4096,2048] @ [3072,2048]^T -> Q,K(roped) in QKVb; V -> VTb transposed
  gemm_bt<1><<<dim3(24, 32), 256, 0, stream>>>(xb, wqT, QKVb, VTb, 4096, 3072, 2048);

  attn<<<dim3(16, 16, 2), 512, 0, stream>>>(QKVb, QKVb + 2048, VTb, AOb);

  gemm_bt<0><<<dim3(16, 32), 256, 0, stream>>>(AOb, woT, (void*)out, nullptr,
                                               4096, 2048, 2048);
}